// Round 8
// baseline (629.162 us; speedup 1.0000x reference)
//
#include <hip/hip_runtime.h>

#define NB   16
#define NN   2048
#define NPTS (NB * NN)
#define KNB  6

typedef __attribute__((ext_vector_type(8))) short short8;
typedef __attribute__((ext_vector_type(4))) float f32x4;
typedef __attribute__((ext_vector_type(16))) float f32x16;
typedef const __attribute__((address_space(4))) float cfloat;

// ---------------- split-precision + squared-norm + self-term fused prep ----------------
// thread = point row: bf16 hi/lo split, |x|^2, and the neighbor-independent
// MLP self-term A[p][op] = (W1a - W1b)*xi + b1 (from the pre-transposed T).
__device__ __forceinline__ unsigned bf16_rne(float f) {
    unsigned u = __float_as_uint(f);
    return (u + 0x7fffu + ((u >> 16) & 1u)) >> 16;
}

template<int C, int COUT>
__global__ __launch_bounds__(256)
void prep_fused(const float* __restrict__ x, const float* __restrict__ T,
                const float* __restrict__ b1,
                unsigned short* __restrict__ Xhi,
                unsigned short* __restrict__ Xlo,
                float* __restrict__ sq, float* __restrict__ A) {
    const int i = blockIdx.x * 256 + threadIdx.x;
    if (i >= NPTS) return;
    float r[C];
    const float4* rp = (const float4*)(x + (size_t)i * C);
#pragma unroll
    for (int c4 = 0; c4 < C / 4; ++c4) {
        float4 f = rp[c4];
        r[4 * c4] = f.x; r[4 * c4 + 1] = f.y; r[4 * c4 + 2] = f.z; r[4 * c4 + 3] = f.w;
    }
    float s = 0.f;
#pragma unroll
    for (int cc = 0; cc < C; cc += 8) {
        short8 vh, vl;
#pragma unroll
        for (int t = 0; t < 8; ++t) {
            const float f = r[cc + t];
            s = fmaf(f, f, s);
            const unsigned h = bf16_rne(f);
            const float hf = __uint_as_float(h << 16);
            const unsigned l = bf16_rne(f - hf);
            vh[t] = (short)h;
            vl[t] = (short)l;
        }
        *(short8*)(Xhi + (size_t)i * C + cc) = vh;
        *(short8*)(Xlo + (size_t)i * C + cc) = vl;
    }
    sq[i] = s;

    cfloat* Tc  = (cfloat*)(uintptr_t)T;
    cfloat* b1c = (cfloat*)(uintptr_t)b1;
    float* Ap = A + (size_t)i * COUT;
#pragma unroll 2
    for (int oq = 0; oq < COUT / 4; ++oq) {
        float av[4];
#pragma unroll
        for (int rr = 0; rr < 4; ++rr) {
            const int op = oq * 4 + rr;
            cfloat* tr = Tc + (size_t)op * (2 * C);
            float a0 = 0.f, a1 = 0.f, a2 = 0.f, a3 = 0.f;
#pragma unroll
            for (int c = 0; c < C; c += 4) {
                a0 = fmaf(tr[c],     r[c],     a0);
                a1 = fmaf(tr[c + 1], r[c + 1], a1);
                a2 = fmaf(tr[c + 2], r[c + 2], a2);
                a3 = fmaf(tr[c + 3], r[c + 3], a3);
            }
            av[rr] = (a0 + a1) + (a2 + a3) + b1c[op];
        }
        *(float4*)(Ap + oq * 4) = make_float4(av[0], av[1], av[2], av[3]);
    }
}

// ---------------- weight prep: T[o][c<CIN] = W1a[c][o]-W1b[c][o]; T[o][CIN+c] = W1b[c][o] ----
__global__ void prep_w(const float* __restrict__ W10, const float* __restrict__ W11,
                       const float* __restrict__ W12,
                       float* __restrict__ T0, float* __restrict__ T1,
                       float* __restrict__ T2) {
    int t = blockIdx.x * 256 + threadIdx.x;
    if (t < 4096) {
        int o = t >> 6, c = t & 63;          // T0/T2: 64 ops x 64 cols (CIN=32)
        float wb0 = W10[(32 + (c & 31)) * 64 + o];
        T0[o * 64 + c] = (c < 32) ? (W10[c * 64 + o] - wb0) : wb0;
        float wb2 = W12[(32 + (c & 31)) * 64 + o];
        T2[o * 64 + c] = (c < 32) ? (W12[c * 64 + o] - wb2) : wb2;
        int o1 = t >> 7, c1 = t & 127;       // T1: 32 ops x 128 cols (CIN=64)
        float wb1 = W11[(64 + (c1 & 63)) * 32 + o1];
        T1[o1 * 128 + c1] = (c1 < 64) ? (W11[c1 * 32 + o1] - wb1) : wb1;
    }
}

// sorted ascending top-6 insert via pure min/max network (2 VALU / level).
__device__ __forceinline__ void insert6f(float s, float* dl) {
#pragma unroll
    for (int k = 0; k < 6; ++k) {
        const float a = dl[k];
        dl[k] = fminf(s, a);
        s = fmaxf(s, a);
    }
}

// ---------------- MFMA kNN scan (32x32 tiles, 8-way split, 64-VGPR diet) ----------------
// wave = 32 queries x 256 candidates (eighth sp). 2048 blocks = 8 blocks/CU
// -> 32 waves/CU IF regs <= 64 (occupancy steps at 64/128). Register diet:
// no software double-buffer (8-wave TLP hides L1/L2 latency instead),
// A-fragments loaded per-kt (8 regs), sq loaded one float4 per 4 rows,
// and for C=64 only B-hi is persistent; B-lo re-read per step from the
// same L1-hot line. Estimated: C=32 ~58 regs, C=64 ~62 regs.
// Embed: e = step*16 + (r&3) + 4*(r>>2) (7 bits) in score low mantissa;
// sublist z = sp*2 + lh (16 sublists x 6 per query); decode in rescore.
template<int C>
__global__ __launch_bounds__(256, 8)
void knn_scan(const unsigned short* __restrict__ Xhi,
              const unsigned short* __restrict__ Xlo,
              const float* __restrict__ sqv,
              unsigned* __restrict__ plist) {
    constexpr int KT = C / 16;              // K=16 tiles per product
    const int w    = __builtin_amdgcn_readfirstlane(threadIdx.x >> 6);
    const int bid  = blockIdx.x;
    const int swz  = ((bid & 7) << 8) | (bid >> 3);   // 2048 blocks, 256/XCD
    const int b    = swz >> 7;              // batch (2 per XCD)
    const int sp   = (swz >> 4) & 7;        // candidate eighth
    const int qg   = swz & 15;              // query group of 4 tiles
    const int qt   = qg * 4 + w;            // this wave's query tile (32 q)
    const int lane = threadIdx.x & 63;
    const int q31  = lane & 31;
    const int lh   = lane >> 5;
    const int base = b * NN;
    const int qloc = qt * 32 + q31;         // batch-local query index

    const unsigned short* qh = Xhi + (size_t)(base + qloc) * C + lh * 8;
    const unsigned short* ql = Xlo + (size_t)(base + qloc) * C + lh * 8;

    short8 bh[KT];
#pragma unroll
    for (int kt = 0; kt < KT; ++kt) bh[kt] = *(const short8*)(qh + kt * 16);

    short8 blp[C == 32 ? KT : 1];
    if constexpr (C == 32) {
#pragma unroll
        for (int kt = 0; kt < KT; ++kt) blp[kt] = *(const short8*)(ql + kt * 16);
    }

    float dl[6];
#pragma unroll
    for (int k = 0; k < 6; ++k) dl[k] = 1e30f;

    const int jbeg   = sp * (NN / 8);
    const int selfjb = qt * 32;             // only step that can contain self

    // walking pointers (candidate rows advance 32 rows/step)
    const unsigned short* arh = Xhi + (size_t)(base + jbeg + q31) * C + lh * 8;
    const unsigned short* arl = Xlo + (size_t)(base + jbeg + q31) * C + lh * 8;
    const float*          sqp = sqv + base + jbeg + lh * 4;

    for (int st = 0; st < NN / 8 / 32; ++st) {
        f32x16 acc = {0.f};
#pragma unroll
        for (int kt = 0; kt < KT; ++kt) {
            const short8 ah = *(const short8*)(arh + kt * 16);
            const short8 al = *(const short8*)(arl + kt * 16);
            const short8 bl = (C == 32) ? blp[C == 32 ? kt : 0]
                                        : *(const short8*)(ql + kt * 16);
            acc = __builtin_amdgcn_mfma_f32_32x32x16_bf16(ah, bh[kt], acc, 0, 0, 0);
            acc = __builtin_amdgcn_mfma_f32_32x32x16_bf16(ah, bl,     acc, 0, 0, 0);
            acc = __builtin_amdgcn_mfma_f32_32x32x16_bf16(al, bh[kt], acc, 0, 0, 0);
        }
        const int jb = jbeg + st * 32;
        const unsigned ebase = (unsigned)(st * 16);
        const bool selfstep = (jb == selfjb);
#pragma unroll
        for (int g4 = 0; g4 < 4; ++g4) {
            const float4 s4 = *(const float4*)(sqp + g4 * 8);
#pragma unroll
            for (int rr = 0; rr < 4; ++rr) {
                const int r = g4 * 4 + rr;
                float sc = fmaf(-2.f, acc[r],
                                rr == 0 ? s4.x : rr == 1 ? s4.y : rr == 2 ? s4.z : s4.w);
                sc = __uint_as_float((__float_as_uint(sc) & 0xFFFFFF00u) |
                                     (ebase + (unsigned)((r & 3) + 4 * (r >> 2))));
                if (selfstep) {
                    const int rowr = (r & 3) + 8 * (r >> 2) + 4 * lh;
                    sc = (rowr == q31) ? 1e30f : sc;
                }
                insert6f(sc, dl);
            }
        }
        arh += 32 * C; arl += 32 * C; sqp += 32;
    }

    // write this lane's sorted sublist as sortable-transformed u32 keys
    // (candidate id stays embedded in the low 8 bits; decoded in rescore).
    unsigned* o = plist + (size_t)(base + qloc) * 96 + (sp * 2 + lh) * 6;
#pragma unroll
    for (int k = 0; k < 6; ++k) {
        const unsigned bits = __float_as_uint(dl[k]);
        o[k] = bits ^ ((bits & 0x80000000u) ? 0xFFFFFFFFu : 0x80000000u);
    }
}

// ---------------- exact rescore: approx top-8 -> exact fp32 top-6 ----------------
// thread = query. Merge 16 sorted 6-sublists (u32 keys tagged with 4-bit z)
// -> approx-best 8 candidates (superset of exact top-6), recompute their
// scores in exact fp32, pick exact top-6 with exact (dist, index) tie-break.
template<int C>
__global__ __launch_bounds__(256)
void rescore(const float* __restrict__ x, const float* __restrict__ sqv,
             const unsigned* __restrict__ plist, int* __restrict__ nbr) {
    const int i = blockIdx.x * 256 + threadIdx.x;
    if (i >= NPTS) return;
    const unsigned* pr = plist + (size_t)i * 96;

    unsigned long long best[8];
#pragma unroll
    for (int k = 0; k < 8; ++k) best[k] = ~0ull;
    for (int z = 0; z < 16; ++z) {
        const unsigned* p = pr + z * 6;
        for (int e = 0; e < 6; ++e) {
            unsigned long long v = ((unsigned long long)p[e] << 4) | (unsigned)z;
            if (v >= best[7]) break;      // sublist ascending
            best[7] = v;
#pragma unroll
            for (int k = 6; k >= 0; --k) {
                if (best[k + 1] < best[k]) {
                    unsigned long long t = best[k]; best[k] = best[k + 1]; best[k + 1] = t;
                }
            }
        }
    }

    const int base = i & ~(NN - 1);
    float4 qv[C / 4];
    const float4* qp = (const float4*)(x + (size_t)i * C);
#pragma unroll
    for (int t = 0; t < C / 4; ++t) qv[t] = qp[t];

    unsigned long long out6[6];
#pragma unroll
    for (int k = 0; k < 6; ++k) out6[k] = ~0ull;

    for (int m = 0; m < 8; ++m) {
        // decode (z, embedded e-bits) -> batch-local candidate index
        const unsigned u32k = (unsigned)(best[m] >> 4);
        const int z = (int)(best[m] & 15ull);
        const unsigned orig = (u32k & 0x80000000u) ? (u32k ^ 0x80000000u) : ~u32k;
        const int e = (int)(orig & 255u);
        const int idx = e & 15;
        const int jloc = (z >> 1) * (NN / 8) + (e >> 4) * 32 +
                         (idx & 3) + 8 * (idx >> 2) + (z & 1) * 4;

        const float4* cp = (const float4*)(x + (size_t)(base + jloc) * C);
        float d0 = 0.f, d1 = 0.f, d2 = 0.f, d3 = 0.f;
#pragma unroll
        for (int t = 0; t < C / 4; ++t) {
            float4 a = cp[t];
            d0 = fmaf(a.x, qv[t].x, d0);
            d1 = fmaf(a.y, qv[t].y, d1);
            d2 = fmaf(a.z, qv[t].z, d2);
            d3 = fmaf(a.w, qv[t].w, d3);
        }
        const float s = fmaf(-2.f, (d0 + d1) + (d2 + d3), sqv[base + jloc]);
        unsigned u = __float_as_uint(s);
        u ^= (u & 0x80000000u) ? 0xFFFFFFFFu : 0x80000000u;
        unsigned long long key = ((unsigned long long)u << 11) | (unsigned)jloc;
#pragma unroll
        for (int k = 0; k < 6; ++k) {
            const unsigned long long ok = out6[k];
            const bool c = key < ok;
            out6[k] = c ? key : ok;
            key     = c ? ok  : key;
        }
    }
#pragma unroll
    for (int k = 0; k < 6; ++k)
        nbr[i * KNB + k] = base + (int)(out6[k] & 2047ull);
}

// ---------------- edge MLP kernel (output-split, hoisted self-term) ----------------
// block = 768 thr = 12 waves = (2 output-halves x 6 neighbors) x 64 points.
// Per thread (proven no-spill shape): h = relu(A[i][op] + W1b[op]*xj)
// for ALL ops (h duplicated across halves), but uacc covers only COUT/2
// outputs. Weights stay on the scalar pipe. 6->1 max via per-half LDS tree.
template<int CIN, int COUT, bool RESID, int MINW>
__global__ __launch_bounds__(768, MINW)
void mlp_kernel(const float* __restrict__ xin, const int* __restrict__ nbr,
                const float* __restrict__ A,  const float* __restrict__ T,
                const float* __restrict__ W2, const float* __restrict__ b2,
                const float* __restrict__ resid, float* __restrict__ out) {
    constexpr int HALF = COUT / 2;
    constexpr int RS = HALF + 4;
    __shared__ float Buf[2][3][64][RS];

    const int tid  = threadIdx.x;
    const int lane = tid & 63;
    const int wv   = __builtin_amdgcn_readfirstlane(tid >> 6);  // 0..11
    const int oh   = wv / 6;                                    // output half
    const int w6   = wv % 6;                                    // neighbor
    const int i    = blockIdx.x * 64 + lane;
    const int j    = nbr[i * KNB + w6];

    float xj[CIN];
    {
        const float4* jp = (const float4*)(xin + (size_t)j * CIN);
#pragma unroll
        for (int c4 = 0; c4 < CIN / 4; ++c4) {
            float4 f = jp[c4];
            xj[4 * c4] = f.x; xj[4 * c4 + 1] = f.y;
            xj[4 * c4 + 2] = f.z; xj[4 * c4 + 3] = f.w;
        }
    }

    float uacc[HALF];
#pragma unroll
    for (int o = 0; o < HALF; ++o) uacc[o] = 0.f;

    cfloat* W1c = (cfloat*)(uintptr_t)T;     // use cols CIN..2CIN (W1b^T)
    cfloat* W2c = (cfloat*)(uintptr_t)W2;
    const float* Ap = A + (size_t)i * COUT;

#pragma unroll 2
    for (int oq = 0; oq < COUT / 4; ++oq) {
        const float4 a4 = *(const float4*)(Ap + 4 * oq);
#pragma unroll
        for (int rr = 0; rr < 4; ++rr) {
            const int op = oq * 4 + rr;
            cfloat* w1r = W1c + (size_t)op * (2 * CIN) + CIN;
            float h0 = 0.f, h1 = 0.f, h2 = 0.f, h3 = 0.f;
#pragma unroll
            for (int c = 0; c < CIN; c += 4) {
                h0 = fmaf(w1r[c],     xj[c],     h0);
                h1 = fmaf(w1r[c + 1], xj[c + 1], h1);
                h2 = fmaf(w1r[c + 2], xj[c + 2], h2);
                h3 = fmaf(w1r[c + 3], xj[c + 3], h3);
            }
            const float aop = rr == 0 ? a4.x : rr == 1 ? a4.y : rr == 2 ? a4.z : a4.w;
            const float h = fmaxf((h0 + h1) + (h2 + h3) + aop, 0.f);
            cfloat* w2r = W2c + (size_t)op * COUT + oh * HALF;
#pragma unroll
            for (int o = 0; o < HALF; ++o)
                uacc[o] = fmaf(w2r[o], h, uacc[o]);
        }
    }

    // per-half 6 -> 1 max tree over neighbor waves
    if (w6 >= 3) {
#pragma unroll
        for (int o = 0; o < HALF; ++o) Buf[oh][w6 - 3][lane][o] = uacc[o];
    }
    __syncthreads();
    if (w6 < 3) {
#pragma unroll
        for (int o = 0; o < HALF; ++o) uacc[o] = fmaxf(uacc[o], Buf[oh][w6][lane][o]);
    }
    __syncthreads();
    if (w6 == 1 || w6 == 2) {
#pragma unroll
        for (int o = 0; o < HALF; ++o) Buf[oh][w6][lane][o] = uacc[o];
    }
    __syncthreads();
    if (w6 == 0) {
        float* po = out + (size_t)i * COUT + oh * HALF;
        const float* b2p = b2 + oh * HALF;
#pragma unroll
        for (int o = 0; o < HALF; ++o) {
            float v = fmaxf(uacc[o], fmaxf(Buf[oh][1][lane][o], Buf[oh][2][lane][o])) + b2p[o];
            if (RESID) v += resid[(size_t)i * COUT + oh * HALF + o];
            po[o] = fmaxf(v, 0.f);
        }
    }
}

extern "C" void kernel_launch(void* const* d_in, const int* in_sizes, int n_in,
                              void* d_out, int out_size, void* d_ws, size_t ws_size,
                              hipStream_t stream) {
    const float* x    = (const float*)d_in[0];
    const float* W1_0 = (const float*)d_in[2];
    const float* b1_0 = (const float*)d_in[3];
    const float* W2_0 = (const float*)d_in[4];
    const float* b2_0 = (const float*)d_in[5];
    const float* W1_1 = (const float*)d_in[6];
    const float* b1_1 = (const float*)d_in[7];
    const float* W2_1 = (const float*)d_in[8];
    const float* b2_1 = (const float*)d_in[9];
    const float* W1_2 = (const float*)d_in[10];
    const float* b1_2 = (const float*)d_in[11];
    const float* W2_2 = (const float*)d_in[12];
    const float* b2_2 = (const float*)d_in[13];
    float* outp = (float*)d_out;

    // workspace layout
    unsigned* plist = (unsigned*)d_ws;                            // NPTS*96 u32
    float* x0  = (float*)(plist + (size_t)NPTS * 96);             // 32768 x 64
    float* x1  = x0 + (size_t)NPTS * 64;                          // 32768 x 32
    float* sqb = x1 + (size_t)NPTS * 32;                          // 32768
    float* T0  = sqb + NPTS;                                      // 64 x 64
    float* T1  = T0 + 4096;                                       // 32 x 128
    float* T2  = T1 + 4096;                                       // 64 x 64
    unsigned short* Xhi = (unsigned short*)(T2 + 4096);           // 32768 x 64 u16
    unsigned short* Xlo = Xhi + (size_t)NPTS * 64;                // 32768 x 64 u16
    int* nbr = (int*)(Xlo + (size_t)NPTS * 64);                   // 32768 x 6
    float* Abuf = (float*)(nbr + (size_t)NPTS * KNB);             // 32768 x 64

    const int sgrid  = NPTS / 256;
    const int scgrid = 2048;            // 8192 waves of 32q x 256c -> 32 waves/CU
    const int pgrid  = NPTS / 64;       // 512 blocks x 768 thr

    prep_w<<<16, 256, 0, stream>>>(W1_0, W1_1, W1_2, T0, T1, T2);

    // ---- layer 0: x (32) -> x0 (64), relu ----
    prep_fused<32, 64><<<sgrid, 256, 0, stream>>>(x, T0, b1_0, Xhi, Xlo, sqb, Abuf);
    knn_scan<32><<<scgrid, 256, 0, stream>>>(Xhi, Xlo, sqb, plist);
    rescore<32><<<sgrid, 256, 0, stream>>>(x, sqb, plist, nbr);
    mlp_kernel<32, 64, false, 5><<<pgrid, 768, 0, stream>>>(x, nbr, Abuf, T0, W2_0, b2_0, nullptr, x0);

    // ---- layer 1: x0 (64) -> x1 (32), relu ----
    prep_fused<64, 32><<<sgrid, 256, 0, stream>>>(x0, T1, b1_1, Xhi, Xlo, sqb, Abuf);
    knn_scan<64><<<scgrid, 256, 0, stream>>>(Xhi, Xlo, sqb, plist);
    rescore<64><<<sgrid, 256, 0, stream>>>(x0, sqb, plist, nbr);
    mlp_kernel<64, 32, false, 4><<<pgrid, 768, 0, stream>>>(x0, nbr, Abuf, T1, W2_1, b2_1, nullptr, x1);

    // ---- layer 2: x1 (32) -> out (64), +x0 residual, relu ----
    prep_fused<32, 64><<<sgrid, 256, 0, stream>>>(x1, T2, b1_2, Xhi, Xlo, sqb, Abuf);
    knn_scan<32><<<scgrid, 256, 0, stream>>>(Xhi, Xlo, sqb, plist);
    rescore<32><<<sgrid, 256, 0, stream>>>(x1, sqb, plist, nbr);
    mlp_kernel<32, 64, true, 5><<<pgrid, 768, 0, stream>>>(x1, nbr, Abuf, T2, W2_2, b2_2, x0, outp);
}

// Round 9
// 555.420 us; speedup vs baseline: 1.1328x; 1.1328x over previous
//
#include <hip/hip_runtime.h>

#define NB   16
#define NN   2048
#define NPTS (NB * NN)
#define KNB  6

typedef __attribute__((ext_vector_type(8))) short short8;
typedef __attribute__((ext_vector_type(4))) float f32x4;
typedef __attribute__((ext_vector_type(16))) float f32x16;
typedef const __attribute__((address_space(4))) float cfloat;

// ---------------- split-precision + squared-norm + self-term fused prep ----------------
__device__ __forceinline__ unsigned bf16_rne(float f) {
    unsigned u = __float_as_uint(f);
    return (u + 0x7fffu + ((u >> 16) & 1u)) >> 16;
}

template<int C, int COUT>
__global__ __launch_bounds__(256)
void prep_fused(const float* __restrict__ x, const float* __restrict__ T,
                const float* __restrict__ b1,
                unsigned short* __restrict__ Xhi,
                unsigned short* __restrict__ Xlo,
                float* __restrict__ sq, float* __restrict__ A) {
    const int i = blockIdx.x * 256 + threadIdx.x;
    if (i >= NPTS) return;
    float r[C];
    const float4* rp = (const float4*)(x + (size_t)i * C);
#pragma unroll
    for (int c4 = 0; c4 < C / 4; ++c4) {
        float4 f = rp[c4];
        r[4 * c4] = f.x; r[4 * c4 + 1] = f.y; r[4 * c4 + 2] = f.z; r[4 * c4 + 3] = f.w;
    }
    float s = 0.f;
#pragma unroll
    for (int cc = 0; cc < C; cc += 8) {
        short8 vh, vl;
#pragma unroll
        for (int t = 0; t < 8; ++t) {
            const float f = r[cc + t];
            s = fmaf(f, f, s);
            const unsigned h = bf16_rne(f);
            const float hf = __uint_as_float(h << 16);
            const unsigned l = bf16_rne(f - hf);
            vh[t] = (short)h;
            vl[t] = (short)l;
        }
        *(short8*)(Xhi + (size_t)i * C + cc) = vh;
        *(short8*)(Xlo + (size_t)i * C + cc) = vl;
    }
    sq[i] = s;

    cfloat* Tc  = (cfloat*)(uintptr_t)T;
    cfloat* b1c = (cfloat*)(uintptr_t)b1;
    float* Ap = A + (size_t)i * COUT;
#pragma unroll 2
    for (int oq = 0; oq < COUT / 4; ++oq) {
        float av[4];
#pragma unroll
        for (int rr = 0; rr < 4; ++rr) {
            const int op = oq * 4 + rr;
            cfloat* tr = Tc + (size_t)op * (2 * C);
            float a0 = 0.f, a1 = 0.f, a2 = 0.f, a3 = 0.f;
#pragma unroll
            for (int c = 0; c < C; c += 4) {
                a0 = fmaf(tr[c],     r[c],     a0);
                a1 = fmaf(tr[c + 1], r[c + 1], a1);
                a2 = fmaf(tr[c + 2], r[c + 2], a2);
                a3 = fmaf(tr[c + 3], r[c + 3], a3);
            }
            av[rr] = (a0 + a1) + (a2 + a3) + b1c[op];
        }
        *(float4*)(Ap + oq * 4) = make_float4(av[0], av[1], av[2], av[3]);
    }
}

// ---------------- weight prep: T[o][c<CIN] = W1a[c][o]-W1b[c][o]; T[o][CIN+c] = W1b[c][o] ----
__global__ void prep_w(const float* __restrict__ W10, const float* __restrict__ W11,
                       const float* __restrict__ W12,
                       float* __restrict__ T0, float* __restrict__ T1,
                       float* __restrict__ T2) {
    int t = blockIdx.x * 256 + threadIdx.x;
    if (t < 4096) {
        int o = t >> 6, c = t & 63;          // T0/T2: 64 ops x 64 cols (CIN=32)
        float wb0 = W10[(32 + (c & 31)) * 64 + o];
        T0[o * 64 + c] = (c < 32) ? (W10[c * 64 + o] - wb0) : wb0;
        float wb2 = W12[(32 + (c & 31)) * 64 + o];
        T2[o * 64 + c] = (c < 32) ? (W12[c * 64 + o] - wb2) : wb2;
        int o1 = t >> 7, c1 = t & 127;       // T1: 32 ops x 128 cols (CIN=64)
        float wb1 = W11[(64 + (c1 & 63)) * 32 + o1];
        T1[o1 * 128 + c1] = (c1 < 64) ? (W11[c1 * 32 + o1] - wb1) : wb1;
    }
}

// sorted ascending top-6 insert via pure min/max network (2 VALU / level).
__device__ __forceinline__ void insert6f(float s, float* dl) {
#pragma unroll
    for (int k = 0; k < 6; ++k) {
        const float a = dl[k];
        dl[k] = fminf(s, a);
        s = fmaxf(s, a);
    }
}

// ---------------- MFMA kNN scan (32x32 tiles, LDS-staged candidates) ----------------
// wave = 32 queries x 512 candidates (quarter sp); block = 4 waves sharing
// the SAME candidate stream -> cooperative async staging via global_load_lds
// (T3/T4: counted s_waitcnt vmcnt(N), never 0 in the main loop; raw
// s_barrier, no __syncthreads drain). LDS step buffer: 32 rows x [hi|lo]
// interleaved, 16B slots, XOR-swizzled slot ^= row&(SR-1) applied BOTH on
// the pre-swizzled global source (stage side) and the ds_read address
// (read side). Double-buffered; 1 (C=32) / 2 (C=64) loads/thread/step.
// Score/insert/selection machinery identical to the verified R7 kernel.
template<int C>
__global__ __launch_bounds__(256, 4)
void knn_scan(const unsigned short* __restrict__ Xhi,
              const unsigned short* __restrict__ Xlo,
              const float* __restrict__ sqv,
              unsigned* __restrict__ plist) {
    constexpr int KT    = C / 16;           // K=16 tiles per product
    constexpr int SR    = C / 4;            // 16B slots per LDS row (hi+lo)
    constexpr int ROWB  = SR * 16;          // 128 / 256 bytes per row
    constexpr int STEPB = 32 * ROWB;        // 4 KB / 8 KB per step buffer
    constexpr int LPT   = STEPB / 16 / 256; // 1 / 2 loads per thread per step
    __shared__ __align__(16) char sm[2 * STEPB];

    const int tid  = threadIdx.x;
    const int w    = __builtin_amdgcn_readfirstlane(tid >> 6);
    const int bid  = blockIdx.x;
    const int swz  = ((bid & 7) << 7) | (bid >> 3);   // 1024 blocks, 128/XCD
    const int b    = swz >> 6;              // batch (2 per XCD)
    const int sp   = (swz >> 4) & 3;        // candidate quarter
    const int qg   = swz & 15;              // query group of 4 tiles
    const int qt   = qg * 4 + w;            // this wave's query tile (32 q)
    const int lane = tid & 63;
    const int q31  = lane & 31;
    const int lh   = lane >> 5;
    const int base = b * NN;
    const int qloc = qt * 32 + q31;         // batch-local query index

    // persistent query fragments
    short8 bh[KT], bl[KT];
#pragma unroll
    for (int kt = 0; kt < KT; ++kt) {
        const size_t off = (size_t)(base + qloc) * C + kt * 16 + lh * 8;
        bh[kt] = *(const short8*)(Xhi + off);
        bl[kt] = *(const short8*)(Xlo + off);
    }

    float dl[6];
#pragma unroll
    for (int k = 0; k < 6; ++k) dl[k] = 1e30f;

    const int jbeg   = sp * (NN / 4);
    const int selfjb = qt * 32;             // only step that can contain self

    // staging source pointers: thread's LDS slot sidx -> (row, slot);
    // content = SRC[row][slot ^ (row&(SR-1))] (XOR involution; reader undoes it)
    const unsigned short* src[LPT];
#pragma unroll
    for (int l = 0; l < LPT; ++l) {
        const int sidx = tid + l * 256;
        const int row  = sidx / SR;
        const int slot = sidx % SR;
        const int u    = slot ^ (row & (SR - 1));
        const unsigned short* bp = (u < SR / 2) ? Xhi : Xlo;
        src[l] = bp + (size_t)(base + jbeg + row) * C + (u & (SR / 2 - 1)) * 8;
    }

    // per-lane ds-read constants
    const int m       = q31 & (SR - 1);
    const int rowbase = q31 * ROWB;
    const float* sqp  = sqv + base + jbeg + lh * 4;
    float4 s4[4];

#define STAGE(BUF) do {                                                        \
    _Pragma("unroll")                                                          \
    for (int l = 0; l < LPT; ++l) {                                            \
        __builtin_amdgcn_global_load_lds(                                      \
            (const __attribute__((address_space(1))) void*)src[l],             \
            (__attribute__((address_space(3))) void*)                          \
                (sm + (BUF) * STEPB + l * 4096 + w * 1024),                    \
            16, 0, 0);                                                         \
        src[l] += 32 * C;                                                      \
    }                                                                          \
} while (0)

#define COMPUTE(BUF, JB) do {                                                  \
    const char* smc = sm + (BUF) * STEPB;                                      \
    f32x16 acc = {0.f};                                                        \
    _Pragma("unroll")                                                          \
    for (int kt = 0; kt < KT; ++kt) {                                          \
        const int uh = kt * 2 + lh;                                            \
        const int ul = 2 * KT + kt * 2 + lh;                                   \
        const short8 ah = *(const short8*)(smc + rowbase + ((uh ^ m) << 4));   \
        const short8 al = *(const short8*)(smc + rowbase + ((ul ^ m) << 4));   \
        acc = __builtin_amdgcn_mfma_f32_32x32x16_bf16(ah, bh[kt], acc, 0, 0, 0); \
        acc = __builtin_amdgcn_mfma_f32_32x32x16_bf16(ah, bl[kt], acc, 0, 0, 0); \
        acc = __builtin_amdgcn_mfma_f32_32x32x16_bf16(al, bh[kt], acc, 0, 0, 0); \
    }                                                                          \
    const unsigned ebase = (unsigned)(((JB) - jbeg) >> 1);   /* step*16 */     \
    const bool selfstep = ((JB) == selfjb);                                    \
    _Pragma("unroll")                                                          \
    for (int g4 = 0; g4 < 4; ++g4) {                                           \
        _Pragma("unroll")                                                      \
        for (int rr = 0; rr < 4; ++rr) {                                       \
            const int r = g4 * 4 + rr;                                         \
            float sc = fmaf(-2.f, acc[r],                                      \
                rr == 0 ? s4[g4].x : rr == 1 ? s4[g4].y :                      \
                rr == 2 ? s4[g4].z : s4[g4].w);                                \
            sc = __uint_as_float((__float_as_uint(sc) & 0xFFFFFF00u) |         \
                                 (ebase + (unsigned)((r & 3) + 4 * (r >> 2)))); \
            if (selfstep) {                                                    \
                const int rowr = (r & 3) + 8 * (r >> 2) + 4 * lh;              \
                sc = (rowr == q31) ? 1e30f : sc;                               \
            }                                                                  \
            insert6f(sc, dl);                                                  \
        }                                                                      \
    }                                                                          \
} while (0)

    STAGE(0);                               // prologue: step 0 in flight
    int jb = jbeg, cur = 0;
#pragma unroll 1
    for (int st = 0; st < 15; ++st) {
        __builtin_amdgcn_s_barrier();       // WAR: all waves done reading buf cur^1
#pragma unroll
        for (int g4 = 0; g4 < 4; ++g4) s4[g4] = *(const float4*)(sqp + g4 * 8);
        asm volatile("" ::: "memory");      // pin: sq loads issue BEFORE stage
        STAGE(cur ^ 1);                     // step st+1 in flight
        if constexpr (C == 32) asm volatile("s_waitcnt vmcnt(1)" ::: "memory");
        else                   asm volatile("s_waitcnt vmcnt(2)" ::: "memory");
        __builtin_amdgcn_s_barrier();       // RAW: all waves' step-st data landed
        COMPUTE(cur, jb);
        jb += 32; sqp += 32; cur ^= 1;
    }
    {   // epilogue: last step, drain
        __builtin_amdgcn_s_barrier();
#pragma unroll
        for (int g4 = 0; g4 < 4; ++g4) s4[g4] = *(const float4*)(sqp + g4 * 8);
        asm volatile("s_waitcnt vmcnt(0)" ::: "memory");
        __builtin_amdgcn_s_barrier();
        COMPUTE(cur, jb);
    }
#undef STAGE
#undef COMPUTE

    // write this lane's sorted sublist as sortable-transformed u32 keys
    unsigned* o = plist + (size_t)(base + qloc) * 48 + (sp * 2 + lh) * 6;
#pragma unroll
    for (int k = 0; k < 6; ++k) {
        const unsigned bits = __float_as_uint(dl[k]);
        o[k] = bits ^ ((bits & 0x80000000u) ? 0xFFFFFFFFu : 0x80000000u);
    }
}

// ---------------- exact rescore: approx top-8 -> exact fp32 top-6 ----------------
// thread = query. Merge 8 sorted 6-sublists (u32 keys tagged with 3-bit z)
// -> approx-best 8 candidates (superset of exact top-6), recompute their
// scores in exact fp32, pick exact top-6 with exact (dist, index) tie-break.
template<int C>
__global__ __launch_bounds__(256)
void rescore(const float* __restrict__ x, const float* __restrict__ sqv,
             const unsigned* __restrict__ plist, int* __restrict__ nbr) {
    const int i = blockIdx.x * 256 + threadIdx.x;
    if (i >= NPTS) return;
    const unsigned* pr = plist + (size_t)i * 48;

    unsigned long long best[8];
#pragma unroll
    for (int k = 0; k < 8; ++k) best[k] = ~0ull;
    for (int z = 0; z < 8; ++z) {
        const unsigned* p = pr + z * 6;
        for (int e = 0; e < 6; ++e) {
            unsigned long long v = ((unsigned long long)p[e] << 3) | (unsigned)z;
            if (v >= best[7]) break;      // sublist ascending
            best[7] = v;
#pragma unroll
            for (int k = 6; k >= 0; --k) {
                if (best[k + 1] < best[k]) {
                    unsigned long long t = best[k]; best[k] = best[k + 1]; best[k + 1] = t;
                }
            }
        }
    }

    const int base = i & ~(NN - 1);
    float4 qv[C / 4];
    const float4* qp = (const float4*)(x + (size_t)i * C);
#pragma unroll
    for (int t = 0; t < C / 4; ++t) qv[t] = qp[t];

    unsigned long long out6[6];
#pragma unroll
    for (int k = 0; k < 6; ++k) out6[k] = ~0ull;

    for (int m = 0; m < 8; ++m) {
        const unsigned u32k = (unsigned)(best[m] >> 3);
        const int z = (int)(best[m] & 7ull);
        const unsigned orig = (u32k & 0x80000000u) ? (u32k ^ 0x80000000u) : ~u32k;
        const int e = (int)(orig & 255u);
        const int idx = e & 15;
        const int jloc = (z >> 1) * (NN / 4) + (e >> 4) * 32 +
                         (idx & 3) + 8 * (idx >> 2) + (z & 1) * 4;

        const float4* cp = (const float4*)(x + (size_t)(base + jloc) * C);
        float d0 = 0.f, d1 = 0.f, d2 = 0.f, d3 = 0.f;
#pragma unroll
        for (int t = 0; t < C / 4; ++t) {
            float4 a = cp[t];
            d0 = fmaf(a.x, qv[t].x, d0);
            d1 = fmaf(a.y, qv[t].y, d1);
            d2 = fmaf(a.z, qv[t].z, d2);
            d3 = fmaf(a.w, qv[t].w, d3);
        }
        const float s = fmaf(-2.f, (d0 + d1) + (d2 + d3), sqv[base + jloc]);
        unsigned u = __float_as_uint(s);
        u ^= (u & 0x80000000u) ? 0xFFFFFFFFu : 0x80000000u;
        unsigned long long key = ((unsigned long long)u << 11) | (unsigned)jloc;
#pragma unroll
        for (int k = 0; k < 6; ++k) {
            const unsigned long long ok = out6[k];
            const bool c = key < ok;
            out6[k] = c ? key : ok;
            key     = c ? ok  : key;
        }
    }
#pragma unroll
    for (int k = 0; k < 6; ++k)
        nbr[i * KNB + k] = base + (int)(out6[k] & 2047ull);
}

// ---------------- edge MLP kernel (output-split, hoisted self-term) ----------------
// block = 768 thr = 12 waves = (2 output-halves x 6 neighbors) x 64 points.
// Per thread (proven no-spill shape): h = relu(A[i][op] + W1b[op]*xj)
// for ALL ops (h duplicated across halves), but uacc covers only COUT/2
// outputs. Weights stay on the scalar pipe. 6->1 max via per-half LDS tree.
template<int CIN, int COUT, bool RESID, int MINW>
__global__ __launch_bounds__(768, MINW)
void mlp_kernel(const float* __restrict__ xin, const int* __restrict__ nbr,
                const float* __restrict__ A,  const float* __restrict__ T,
                const float* __restrict__ W2, const float* __restrict__ b2,
                const float* __restrict__ resid, float* __restrict__ out) {
    constexpr int HALF = COUT / 2;
    constexpr int RS = HALF + 4;
    __shared__ float Buf[2][3][64][RS];

    const int tid  = threadIdx.x;
    const int lane = tid & 63;
    const int wv   = __builtin_amdgcn_readfirstlane(tid >> 6);  // 0..11
    const int oh   = wv / 6;                                    // output half
    const int w6   = wv % 6;                                    // neighbor
    const int i    = blockIdx.x * 64 + lane;
    const int j    = nbr[i * KNB + w6];

    float xj[CIN];
    {
        const float4* jp = (const float4*)(xin + (size_t)j * CIN);
#pragma unroll
        for (int c4 = 0; c4 < CIN / 4; ++c4) {
            float4 f = jp[c4];
            xj[4 * c4] = f.x; xj[4 * c4 + 1] = f.y;
            xj[4 * c4 + 2] = f.z; xj[4 * c4 + 3] = f.w;
        }
    }

    float uacc[HALF];
#pragma unroll
    for (int o = 0; o < HALF; ++o) uacc[o] = 0.f;

    cfloat* W1c = (cfloat*)(uintptr_t)T;     // use cols CIN..2CIN (W1b^T)
    cfloat* W2c = (cfloat*)(uintptr_t)W2;
    const float* Ap = A + (size_t)i * COUT;

#pragma unroll 2
    for (int oq = 0; oq < COUT / 4; ++oq) {
        const float4 a4 = *(const float4*)(Ap + 4 * oq);
#pragma unroll
        for (int rr = 0; rr < 4; ++rr) {
            const int op = oq * 4 + rr;
            cfloat* w1r = W1c + (size_t)op * (2 * CIN) + CIN;
            float h0 = 0.f, h1 = 0.f, h2 = 0.f, h3 = 0.f;
#pragma unroll
            for (int c = 0; c < CIN; c += 4) {
                h0 = fmaf(w1r[c],     xj[c],     h0);
                h1 = fmaf(w1r[c + 1], xj[c + 1], h1);
                h2 = fmaf(w1r[c + 2], xj[c + 2], h2);
                h3 = fmaf(w1r[c + 3], xj[c + 3], h3);
            }
            const float aop = rr == 0 ? a4.x : rr == 1 ? a4.y : rr == 2 ? a4.z : a4.w;
            const float h = fmaxf((h0 + h1) + (h2 + h3) + aop, 0.f);
            cfloat* w2r = W2c + (size_t)op * COUT + oh * HALF;
#pragma unroll
            for (int o = 0; o < HALF; ++o)
                uacc[o] = fmaf(w2r[o], h, uacc[o]);
        }
    }

    // per-half 6 -> 1 max tree over neighbor waves
    if (w6 >= 3) {
#pragma unroll
        for (int o = 0; o < HALF; ++o) Buf[oh][w6 - 3][lane][o] = uacc[o];
    }
    __syncthreads();
    if (w6 < 3) {
#pragma unroll
        for (int o = 0; o < HALF; ++o) uacc[o] = fmaxf(uacc[o], Buf[oh][w6][lane][o]);
    }
    __syncthreads();
    if (w6 == 1 || w6 == 2) {
#pragma unroll
        for (int o = 0; o < HALF; ++o) Buf[oh][w6][lane][o] = uacc[o];
    }
    __syncthreads();
    if (w6 == 0) {
        float* po = out + (size_t)i * COUT + oh * HALF;
        const float* b2p = b2 + oh * HALF;
#pragma unroll
        for (int o = 0; o < HALF; ++o) {
            float v = fmaxf(uacc[o], fmaxf(Buf[oh][1][lane][o], Buf[oh][2][lane][o])) + b2p[o];
            if (RESID) v += resid[(size_t)i * COUT + oh * HALF + o];
            po[o] = fmaxf(v, 0.f);
        }
    }
}

extern "C" void kernel_launch(void* const* d_in, const int* in_sizes, int n_in,
                              void* d_out, int out_size, void* d_ws, size_t ws_size,
                              hipStream_t stream) {
    const float* x    = (const float*)d_in[0];
    const float* W1_0 = (const float*)d_in[2];
    const float* b1_0 = (const float*)d_in[3];
    const float* W2_0 = (const float*)d_in[4];
    const float* b2_0 = (const float*)d_in[5];
    const float* W1_1 = (const float*)d_in[6];
    const float* b1_1 = (const float*)d_in[7];
    const float* W2_1 = (const float*)d_in[8];
    const float* b2_1 = (const float*)d_in[9];
    const float* W1_2 = (const float*)d_in[10];
    const float* b1_2 = (const float*)d_in[11];
    const float* W2_2 = (const float*)d_in[12];
    const float* b2_2 = (const float*)d_in[13];
    float* outp = (float*)d_out;

    // workspace layout
    unsigned* plist = (unsigned*)d_ws;                            // NPTS*48 u32
    float* x0  = (float*)(plist + (size_t)NPTS * 48);             // 32768 x 64
    float* x1  = x0 + (size_t)NPTS * 64;                          // 32768 x 32
    float* sqb = x1 + (size_t)NPTS * 32;                          // 32768
    float* T0  = sqb + NPTS;                                      // 64 x 64
    float* T1  = T0 + 4096;                                       // 32 x 128
    float* T2  = T1 + 4096;                                       // 64 x 64
    unsigned short* Xhi = (unsigned short*)(T2 + 4096);           // 32768 x 64 u16
    unsigned short* Xlo = Xhi + (size_t)NPTS * 64;                // 32768 x 64 u16
    int* nbr = (int*)(Xlo + (size_t)NPTS * 64);                   // 32768 x 6
    float* Abuf = (float*)(nbr + (size_t)NPTS * KNB);             // 32768 x 64

    const int sgrid  = NPTS / 256;
    const int scgrid = 1024;            // 4096 waves of 32q x 512c
    const int pgrid  = NPTS / 64;       // 512 blocks x 768 thr

    prep_w<<<16, 256, 0, stream>>>(W1_0, W1_1, W1_2, T0, T1, T2);

    // ---- layer 0: x (32) -> x0 (64), relu ----
    prep_fused<32, 64><<<sgrid, 256, 0, stream>>>(x, T0, b1_0, Xhi, Xlo, sqb, Abuf);
    knn_scan<32><<<scgrid, 256, 0, stream>>>(Xhi, Xlo, sqb, plist);
    rescore<32><<<sgrid, 256, 0, stream>>>(x, sqb, plist, nbr);
    mlp_kernel<32, 64, false, 5><<<pgrid, 768, 0, stream>>>(x, nbr, Abuf, T0, W2_0, b2_0, nullptr, x0);

    // ---- layer 1: x0 (64) -> x1 (32), relu ----
    prep_fused<64, 32><<<sgrid, 256, 0, stream>>>(x0, T1, b1_1, Xhi, Xlo, sqb, Abuf);
    knn_scan<64><<<scgrid, 256, 0, stream>>>(Xhi, Xlo, sqb, plist);
    rescore<64><<<sgrid, 256, 0, stream>>>(x0, sqb, plist, nbr);
    mlp_kernel<64, 32, false, 4><<<pgrid, 768, 0, stream>>>(x0, nbr, Abuf, T1, W2_1, b2_1, nullptr, x1);

    // ---- layer 2: x1 (32) -> out (64), +x0 residual, relu ----
    prep_fused<32, 64><<<sgrid, 256, 0, stream>>>(x1, T2, b1_2, Xhi, Xlo, sqb, Abuf);
    knn_scan<32><<<scgrid, 256, 0, stream>>>(Xhi, Xlo, sqb, plist);
    rescore<32><<<sgrid, 256, 0, stream>>>(x1, sqb, plist, nbr);
    mlp_kernel<32, 64, true, 5><<<pgrid, 768, 0, stream>>>(x1, nbr, Abuf, T2, W2_2, b2_2, x0, outp);
}

// Round 10
// 534.585 us; speedup vs baseline: 1.1769x; 1.0390x over previous
//
#include <hip/hip_runtime.h>

#define NB   16
#define NN   2048
#define NPTS (NB * NN)
#define KNB  6

typedef __attribute__((ext_vector_type(8))) short short8;
typedef __attribute__((ext_vector_type(4))) float f32x4;
typedef __attribute__((ext_vector_type(16))) float f32x16;
typedef const __attribute__((address_space(4))) float cfloat;

// ---------------- split-precision + squared-norm + self-term fused prep ----------------
__device__ __forceinline__ unsigned bf16_rne(float f) {
    unsigned u = __float_as_uint(f);
    return (u + 0x7fffu + ((u >> 16) & 1u)) >> 16;
}

template<int C, int COUT>
__global__ __launch_bounds__(256)
void prep_fused(const float* __restrict__ x, const float* __restrict__ T,
                const float* __restrict__ b1,
                unsigned short* __restrict__ Xhi,
                unsigned short* __restrict__ Xlo,
                float* __restrict__ sq, float* __restrict__ A) {
    const int i = blockIdx.x * 256 + threadIdx.x;
    if (i >= NPTS) return;
    float r[C];
    const float4* rp = (const float4*)(x + (size_t)i * C);
#pragma unroll
    for (int c4 = 0; c4 < C / 4; ++c4) {
        float4 f = rp[c4];
        r[4 * c4] = f.x; r[4 * c4 + 1] = f.y; r[4 * c4 + 2] = f.z; r[4 * c4 + 3] = f.w;
    }
    float s = 0.f;
#pragma unroll
    for (int cc = 0; cc < C; cc += 8) {
        short8 vh, vl;
#pragma unroll
        for (int t = 0; t < 8; ++t) {
            const float f = r[cc + t];
            s = fmaf(f, f, s);
            const unsigned h = bf16_rne(f);
            const float hf = __uint_as_float(h << 16);
            const unsigned l = bf16_rne(f - hf);
            vh[t] = (short)h;
            vl[t] = (short)l;
        }
        *(short8*)(Xhi + (size_t)i * C + cc) = vh;
        *(short8*)(Xlo + (size_t)i * C + cc) = vl;
    }
    sq[i] = s;

    cfloat* Tc  = (cfloat*)(uintptr_t)T;
    cfloat* b1c = (cfloat*)(uintptr_t)b1;
    float* Ap = A + (size_t)i * COUT;
#pragma unroll 2
    for (int oq = 0; oq < COUT / 4; ++oq) {
        float av[4];
#pragma unroll
        for (int rr = 0; rr < 4; ++rr) {
            const int op = oq * 4 + rr;
            cfloat* tr = Tc + (size_t)op * (2 * C);
            float a0 = 0.f, a1 = 0.f, a2 = 0.f, a3 = 0.f;
#pragma unroll
            for (int c = 0; c < C; c += 4) {
                a0 = fmaf(tr[c],     r[c],     a0);
                a1 = fmaf(tr[c + 1], r[c + 1], a1);
                a2 = fmaf(tr[c + 2], r[c + 2], a2);
                a3 = fmaf(tr[c + 3], r[c + 3], a3);
            }
            av[rr] = (a0 + a1) + (a2 + a3) + b1c[op];
        }
        *(float4*)(Ap + oq * 4) = make_float4(av[0], av[1], av[2], av[3]);
    }
}

// ---------------- weight prep: T[o][c<CIN] = W1a[c][o]-W1b[c][o]; T[o][CIN+c] = W1b[c][o] ----
__global__ void prep_w(const float* __restrict__ W10, const float* __restrict__ W11,
                       const float* __restrict__ W12,
                       float* __restrict__ T0, float* __restrict__ T1,
                       float* __restrict__ T2) {
    int t = blockIdx.x * 256 + threadIdx.x;
    if (t < 4096) {
        int o = t >> 6, c = t & 63;          // T0/T2: 64 ops x 64 cols (CIN=32)
        float wb0 = W10[(32 + (c & 31)) * 64 + o];
        T0[o * 64 + c] = (c < 32) ? (W10[c * 64 + o] - wb0) : wb0;
        float wb2 = W12[(32 + (c & 31)) * 64 + o];
        T2[o * 64 + c] = (c < 32) ? (W12[c * 64 + o] - wb2) : wb2;
        int o1 = t >> 7, c1 = t & 127;       // T1: 32 ops x 128 cols (CIN=64)
        float wb1 = W11[(64 + (c1 & 63)) * 32 + o1];
        T1[o1 * 128 + c1] = (c1 < 64) ? (W11[c1 * 32 + o1] - wb1) : wb1;
    }
}

// sorted ascending top-6 insert via pure min/max network (2 VALU / level).
__device__ __forceinline__ void insert6f(float s, float* dl) {
#pragma unroll
    for (int k = 0; k < 6; ++k) {
        const float a = dl[k];
        dl[k] = fminf(s, a);
        s = fmaxf(s, a);
    }
}

// ---------------- MFMA kNN scan (32x32 tiles, LDS-staged candidates) ----------------
// (unchanged from R9 — verified: took knn out of the top-5)
template<int C>
__global__ __launch_bounds__(256, 4)
void knn_scan(const unsigned short* __restrict__ Xhi,
              const unsigned short* __restrict__ Xlo,
              const float* __restrict__ sqv,
              unsigned* __restrict__ plist) {
    constexpr int KT    = C / 16;           // K=16 tiles per product
    constexpr int SR    = C / 4;            // 16B slots per LDS row (hi+lo)
    constexpr int ROWB  = SR * 16;          // 128 / 256 bytes per row
    constexpr int STEPB = 32 * ROWB;        // 4 KB / 8 KB per step buffer
    constexpr int LPT   = STEPB / 16 / 256; // 1 / 2 loads per thread per step
    __shared__ __align__(16) char sm[2 * STEPB];

    const int tid  = threadIdx.x;
    const int w    = __builtin_amdgcn_readfirstlane(tid >> 6);
    const int bid  = blockIdx.x;
    const int swz  = ((bid & 7) << 7) | (bid >> 3);   // 1024 blocks, 128/XCD
    const int b    = swz >> 6;              // batch (2 per XCD)
    const int sp   = (swz >> 4) & 3;        // candidate quarter
    const int qg   = swz & 15;              // query group of 4 tiles
    const int qt   = qg * 4 + w;            // this wave's query tile (32 q)
    const int lane = tid & 63;
    const int q31  = lane & 31;
    const int lh   = lane >> 5;
    const int base = b * NN;
    const int qloc = qt * 32 + q31;         // batch-local query index

    // persistent query fragments
    short8 bh[KT], bl[KT];
#pragma unroll
    for (int kt = 0; kt < KT; ++kt) {
        const size_t off = (size_t)(base + qloc) * C + kt * 16 + lh * 8;
        bh[kt] = *(const short8*)(Xhi + off);
        bl[kt] = *(const short8*)(Xlo + off);
    }

    float dl[6];
#pragma unroll
    for (int k = 0; k < 6; ++k) dl[k] = 1e30f;

    const int jbeg   = sp * (NN / 4);
    const int selfjb = qt * 32;             // only step that can contain self

    // staging source pointers: thread's LDS slot sidx -> (row, slot);
    // content = SRC[row][slot ^ (row&(SR-1))] (XOR involution; reader undoes it)
    const unsigned short* src[LPT];
#pragma unroll
    for (int l = 0; l < LPT; ++l) {
        const int sidx = tid + l * 256;
        const int row  = sidx / SR;
        const int slot = sidx % SR;
        const int u    = slot ^ (row & (SR - 1));
        const unsigned short* bp = (u < SR / 2) ? Xhi : Xlo;
        src[l] = bp + (size_t)(base + jbeg + row) * C + (u & (SR / 2 - 1)) * 8;
    }

    // per-lane ds-read constants
    const int m       = q31 & (SR - 1);
    const int rowbase = q31 * ROWB;
    const float* sqp  = sqv + base + jbeg + lh * 4;
    float4 s4[4];

#define STAGE(BUF) do {                                                        \
    _Pragma("unroll")                                                          \
    for (int l = 0; l < LPT; ++l) {                                            \
        __builtin_amdgcn_global_load_lds(                                      \
            (const __attribute__((address_space(1))) void*)src[l],             \
            (__attribute__((address_space(3))) void*)                          \
                (sm + (BUF) * STEPB + l * 4096 + w * 1024),                    \
            16, 0, 0);                                                         \
        src[l] += 32 * C;                                                      \
    }                                                                          \
} while (0)

#define COMPUTE(BUF, JB) do {                                                  \
    const char* smc = sm + (BUF) * STEPB;                                      \
    f32x16 acc = {0.f};                                                        \
    _Pragma("unroll")                                                          \
    for (int kt = 0; kt < KT; ++kt) {                                          \
        const int uh = kt * 2 + lh;                                            \
        const int ul = 2 * KT + kt * 2 + lh;                                   \
        const short8 ah = *(const short8*)(smc + rowbase + ((uh ^ m) << 4));   \
        const short8 al = *(const short8*)(smc + rowbase + ((ul ^ m) << 4));   \
        acc = __builtin_amdgcn_mfma_f32_32x32x16_bf16(ah, bh[kt], acc, 0, 0, 0); \
        acc = __builtin_amdgcn_mfma_f32_32x32x16_bf16(ah, bl[kt], acc, 0, 0, 0); \
        acc = __builtin_amdgcn_mfma_f32_32x32x16_bf16(al, bh[kt], acc, 0, 0, 0); \
    }                                                                          \
    const unsigned ebase = (unsigned)(((JB) - jbeg) >> 1);   /* step*16 */     \
    const bool selfstep = ((JB) == selfjb);                                    \
    _Pragma("unroll")                                                          \
    for (int g4 = 0; g4 < 4; ++g4) {                                           \
        _Pragma("unroll")                                                      \
        for (int rr = 0; rr < 4; ++rr) {                                       \
            const int r = g4 * 4 + rr;                                         \
            float sc = fmaf(-2.f, acc[r],                                      \
                rr == 0 ? s4[g4].x : rr == 1 ? s4[g4].y :                      \
                rr == 2 ? s4[g4].z : s4[g4].w);                                \
            sc = __uint_as_float((__float_as_uint(sc) & 0xFFFFFF00u) |         \
                                 (ebase + (unsigned)((r & 3) + 4 * (r >> 2)))); \
            if (selfstep) {                                                    \
                const int rowr = (r & 3) + 8 * (r >> 2) + 4 * lh;              \
                sc = (rowr == q31) ? 1e30f : sc;                               \
            }                                                                  \
            insert6f(sc, dl);                                                  \
        }                                                                      \
    }                                                                          \
} while (0)

    STAGE(0);                               // prologue: step 0 in flight
    int jb = jbeg, cur = 0;
#pragma unroll 1
    for (int st = 0; st < 15; ++st) {
        __builtin_amdgcn_s_barrier();       // WAR: all waves done reading buf cur^1
#pragma unroll
        for (int g4 = 0; g4 < 4; ++g4) s4[g4] = *(const float4*)(sqp + g4 * 8);
        asm volatile("" ::: "memory");      // pin: sq loads issue BEFORE stage
        STAGE(cur ^ 1);                     // step st+1 in flight
        if constexpr (C == 32) asm volatile("s_waitcnt vmcnt(1)" ::: "memory");
        else                   asm volatile("s_waitcnt vmcnt(2)" ::: "memory");
        __builtin_amdgcn_s_barrier();       // RAW: all waves' step-st data landed
        COMPUTE(cur, jb);
        jb += 32; sqp += 32; cur ^= 1;
    }
    {   // epilogue: last step, drain
        __builtin_amdgcn_s_barrier();
#pragma unroll
        for (int g4 = 0; g4 < 4; ++g4) s4[g4] = *(const float4*)(sqp + g4 * 8);
        asm volatile("s_waitcnt vmcnt(0)" ::: "memory");
        __builtin_amdgcn_s_barrier();
        COMPUTE(cur, jb);
    }
#undef STAGE
#undef COMPUTE

    // write this lane's sorted sublist as sortable-transformed u32 keys
    unsigned* o = plist + (size_t)(base + qloc) * 48 + (sp * 2 + lh) * 6;
#pragma unroll
    for (int k = 0; k < 6; ++k) {
        const unsigned bits = __float_as_uint(dl[k]);
        o[k] = bits ^ ((bits & 0x80000000u) ? 0xFFFFFFFFu : 0x80000000u);
    }
}

// ---------------- exact rescore: approx top-8 -> exact fp32 top-6 ----------------
template<int C>
__global__ __launch_bounds__(256)
void rescore(const float* __restrict__ x, const float* __restrict__ sqv,
             const unsigned* __restrict__ plist, int* __restrict__ nbr) {
    const int i = blockIdx.x * 256 + threadIdx.x;
    if (i >= NPTS) return;
    const unsigned* pr = plist + (size_t)i * 48;

    unsigned long long best[8];
#pragma unroll
    for (int k = 0; k < 8; ++k) best[k] = ~0ull;
    for (int z = 0; z < 8; ++z) {
        const unsigned* p = pr + z * 6;
        for (int e = 0; e < 6; ++e) {
            unsigned long long v = ((unsigned long long)p[e] << 3) | (unsigned)z;
            if (v >= best[7]) break;      // sublist ascending
            best[7] = v;
#pragma unroll
            for (int k = 6; k >= 0; --k) {
                if (best[k + 1] < best[k]) {
                    unsigned long long t = best[k]; best[k] = best[k + 1]; best[k + 1] = t;
                }
            }
        }
    }

    const int base = i & ~(NN - 1);
    float4 qv[C / 4];
    const float4* qp = (const float4*)(x + (size_t)i * C);
#pragma unroll
    for (int t = 0; t < C / 4; ++t) qv[t] = qp[t];

    unsigned long long out6[6];
#pragma unroll
    for (int k = 0; k < 6; ++k) out6[k] = ~0ull;

    for (int m = 0; m < 8; ++m) {
        const unsigned u32k = (unsigned)(best[m] >> 3);
        const int z = (int)(best[m] & 7ull);
        const unsigned orig = (u32k & 0x80000000u) ? (u32k ^ 0x80000000u) : ~u32k;
        const int e = (int)(orig & 255u);
        const int idx = e & 15;
        const int jloc = (z >> 1) * (NN / 4) + (e >> 4) * 32 +
                         (idx & 3) + 8 * (idx >> 2) + (z & 1) * 4;

        const float4* cp = (const float4*)(x + (size_t)(base + jloc) * C);
        float d0 = 0.f, d1 = 0.f, d2 = 0.f, d3 = 0.f;
#pragma unroll
        for (int t = 0; t < C / 4; ++t) {
            float4 a = cp[t];
            d0 = fmaf(a.x, qv[t].x, d0);
            d1 = fmaf(a.y, qv[t].y, d1);
            d2 = fmaf(a.z, qv[t].z, d2);
            d3 = fmaf(a.w, qv[t].w, d3);
        }
        const float s = fmaf(-2.f, (d0 + d1) + (d2 + d3), sqv[base + jloc]);
        unsigned u = __float_as_uint(s);
        u ^= (u & 0x80000000u) ? 0xFFFFFFFFu : 0x80000000u;
        unsigned long long key = ((unsigned long long)u << 11) | (unsigned)jloc;
#pragma unroll
        for (int k = 0; k < 6; ++k) {
            const unsigned long long ok = out6[k];
            const bool c = key < ok;
            out6[k] = c ? key : ok;
            key     = c ? ok  : key;
        }
    }
#pragma unroll
    for (int k = 0; k < 6; ++k)
        nbr[i * KNB + k] = base + (int)(out6[k] & 2047ull);
}

// ---------------- edge MLP kernel (output-split + wave op-stagger + XCD swizzle) ----------------
// block = 768 thr = 12 waves = (2 output-halves x 6 neighbors) x 64 points.
// R9 PMC: VALUBusy 33%, dur 69us -- all 24 resident waves/CU walk the SAME
// ~24KB weight stream in lockstep, so per-op scalar K$/L2 misses SERIALIZE.
// Fix 1: per-wave op rotation (qofs = wv*3 mod NQ) -- waves touch different
// weight lines concurrently; each line fetched once stays warm for the rest.
// Fix 2: XCD-swizzled block id (512%8==0, bijective) -- 64 consecutive
// blocks = 2 batches (~1-2MB gather set) per XCD L2 (R9: L1-mlp FETCH 16.5MB
// vs 8MB input = cross-XCD thrash).
template<int CIN, int COUT, bool RESID, int MINW>
__global__ __launch_bounds__(768, MINW)
void mlp_kernel(const float* __restrict__ xin, const int* __restrict__ nbr,
                const float* __restrict__ A,  const float* __restrict__ T,
                const float* __restrict__ W2, const float* __restrict__ b2,
                const float* __restrict__ resid, float* __restrict__ out) {
    constexpr int HALF = COUT / 2;
    constexpr int NQ   = COUT / 4;
    constexpr int RS = HALF + 4;
    __shared__ float Buf[2][3][64][RS];

    const int tid  = threadIdx.x;
    const int lane = tid & 63;
    const int wv   = __builtin_amdgcn_readfirstlane(tid >> 6);  // 0..11
    const int oh   = wv / 6;                                    // output half
    const int w6   = wv % 6;                                    // neighbor
    const int bid  = blockIdx.x;
    const int bsw  = ((bid & 7) << 6) | (bid >> 3);             // XCD swizzle, 512 blocks
    const int i    = bsw * 64 + lane;
    const int j    = nbr[i * KNB + w6];

    float xj[CIN];
    {
        const float4* jp = (const float4*)(xin + (size_t)j * CIN);
#pragma unroll
        for (int c4 = 0; c4 < CIN / 4; ++c4) {
            float4 f = jp[c4];
            xj[4 * c4] = f.x; xj[4 * c4 + 1] = f.y;
            xj[4 * c4 + 2] = f.z; xj[4 * c4 + 3] = f.w;
        }
    }

    float uacc[HALF];
#pragma unroll
    for (int o = 0; o < HALF; ++o) uacc[o] = 0.f;

    cfloat* W1c = (cfloat*)(uintptr_t)T;     // use cols CIN..2CIN (W1b^T)
    cfloat* W2c = (cfloat*)(uintptr_t)W2;
    const float* Ap = A + (size_t)i * COUT;

    const int qofs = (wv * 3) & (NQ - 1);    // wave-staggered op start

#pragma unroll 2
    for (int qi = 0; qi < NQ; ++qi) {
        const int oq = (qi + qofs) & (NQ - 1);
        const float4 a4 = *(const float4*)(Ap + 4 * oq);
#pragma unroll
        for (int rr = 0; rr < 4; ++rr) {
            const int op = oq * 4 + rr;
            cfloat* w1r = W1c + (size_t)op * (2 * CIN) + CIN;
            float h0 = 0.f, h1 = 0.f, h2 = 0.f, h3 = 0.f;
#pragma unroll
            for (int c = 0; c < CIN; c += 4) {
                h0 = fmaf(w1r[c],     xj[c],     h0);
                h1 = fmaf(w1r[c + 1], xj[c + 1], h1);
                h2 = fmaf(w1r[c + 2], xj[c + 2], h2);
                h3 = fmaf(w1r[c + 3], xj[c + 3], h3);
            }
            const float aop = rr == 0 ? a4.x : rr == 1 ? a4.y : rr == 2 ? a4.z : a4.w;
            const float h = fmaxf((h0 + h1) + (h2 + h3) + aop, 0.f);
            cfloat* w2r = W2c + (size_t)op * COUT + oh * HALF;
#pragma unroll
            for (int o = 0; o < HALF; ++o)
                uacc[o] = fmaf(w2r[o], h, uacc[o]);
        }
    }

    // per-half 6 -> 1 max tree over neighbor waves
    if (w6 >= 3) {
#pragma unroll
        for (int o = 0; o < HALF; ++o) Buf[oh][w6 - 3][lane][o] = uacc[o];
    }
    __syncthreads();
    if (w6 < 3) {
#pragma unroll
        for (int o = 0; o < HALF; ++o) uacc[o] = fmaxf(uacc[o], Buf[oh][w6][lane][o]);
    }
    __syncthreads();
    if (w6 == 1 || w6 == 2) {
#pragma unroll
        for (int o = 0; o < HALF; ++o) Buf[oh][w6][lane][o] = uacc[o];
    }
    __syncthreads();
    if (w6 == 0) {
        float* po = out + (size_t)i * COUT + oh * HALF;
        const float* b2p = b2 + oh * HALF;
#pragma unroll
        for (int o = 0; o < HALF; ++o) {
            float v = fmaxf(uacc[o], fmaxf(Buf[oh][1][lane][o], Buf[oh][2][lane][o])) + b2p[o];
            if (RESID) v += resid[(size_t)i * COUT + oh * HALF + o];
            po[o] = fmaxf(v, 0.f);
        }
    }
}

extern "C" void kernel_launch(void* const* d_in, const int* in_sizes, int n_in,
                              void* d_out, int out_size, void* d_ws, size_t ws_size,
                              hipStream_t stream) {
    const float* x    = (const float*)d_in[0];
    const float* W1_0 = (const float*)d_in[2];
    const float* b1_0 = (const float*)d_in[3];
    const float* W2_0 = (const float*)d_in[4];
    const float* b2_0 = (const float*)d_in[5];
    const float* W1_1 = (const float*)d_in[6];
    const float* b1_1 = (const float*)d_in[7];
    const float* W2_1 = (const float*)d_in[8];
    const float* b2_1 = (const float*)d_in[9];
    const float* W1_2 = (const float*)d_in[10];
    const float* b1_2 = (const float*)d_in[11];
    const float* W2_2 = (const float*)d_in[12];
    const float* b2_2 = (const float*)d_in[13];
    float* outp = (float*)d_out;

    // workspace layout
    unsigned* plist = (unsigned*)d_ws;                            // NPTS*48 u32
    float* x0  = (float*)(plist + (size_t)NPTS * 48);             // 32768 x 64
    float* x1  = x0 + (size_t)NPTS * 64;                          // 32768 x 32
    float* sqb = x1 + (size_t)NPTS * 32;                          // 32768
    float* T0  = sqb + NPTS;                                      // 64 x 64
    float* T1  = T0 + 4096;                                       // 32 x 128
    float* T2  = T1 + 4096;                                       // 64 x 64
    unsigned short* Xhi = (unsigned short*)(T2 + 4096);           // 32768 x 64 u16
    unsigned short* Xlo = Xhi + (size_t)NPTS * 64;                // 32768 x 64 u16
    int* nbr = (int*)(Xlo + (size_t)NPTS * 64);                   // 32768 x 6
    float* Abuf = (float*)(nbr + (size_t)NPTS * KNB);             // 32768 x 64

    const int sgrid  = NPTS / 256;
    const int scgrid = 1024;            // 4096 waves of 32q x 512c
    const int pgrid  = NPTS / 64;       // 512 blocks x 768 thr

    prep_w<<<16, 256, 0, stream>>>(W1_0, W1_1, W1_2, T0, T1, T2);

    // ---- layer 0: x (32) -> x0 (64), relu ----
    prep_fused<32, 64><<<sgrid, 256, 0, stream>>>(x, T0, b1_0, Xhi, Xlo, sqb, Abuf);
    knn_scan<32><<<scgrid, 256, 0, stream>>>(Xhi, Xlo, sqb, plist);
    rescore<32><<<sgrid, 256, 0, stream>>>(x, sqb, plist, nbr);
    mlp_kernel<32, 64, false, 5><<<pgrid, 768, 0, stream>>>(x, nbr, Abuf, T0, W2_0, b2_0, nullptr, x0);

    // ---- layer 1: x0 (64) -> x1 (32), relu ----
    prep_fused<64, 32><<<sgrid, 256, 0, stream>>>(x0, T1, b1_1, Xhi, Xlo, sqb, Abuf);
    knn_scan<64><<<scgrid, 256, 0, stream>>>(Xhi, Xlo, sqb, plist);
    rescore<64><<<sgrid, 256, 0, stream>>>(x0, sqb, plist, nbr);
    mlp_kernel<64, 32, false, 4><<<pgrid, 768, 0, stream>>>(x0, nbr, Abuf, T1, W2_1, b2_1, nullptr, x1);

    // ---- layer 2: x1 (32) -> out (64), +x0 residual, relu ----
    prep_fused<32, 64><<<sgrid, 256, 0, stream>>>(x1, T2, b1_2, Xhi, Xlo, sqb, Abuf);
    knn_scan<32><<<scgrid, 256, 0, stream>>>(Xhi, Xlo, sqb, plist);
    rescore<32><<<sgrid, 256, 0, stream>>>(x1, sqb, plist, nbr);
    mlp_kernel<32, 64, true, 5><<<pgrid, 768, 0, stream>>>(x1, nbr, Abuf, T2, W2_2, b2_2, x0, outp);
}

// Round 11
// 525.047 us; speedup vs baseline: 1.1983x; 1.0182x over previous
//
#include <hip/hip_runtime.h>

#define NB   16
#define NN   2048
#define NPTS (NB * NN)
#define KNB  6

typedef __attribute__((ext_vector_type(8))) short short8;
typedef __attribute__((ext_vector_type(4))) float f32x4;
typedef __attribute__((ext_vector_type(16))) float f32x16;
typedef const __attribute__((address_space(4))) float cfloat;

// ---------------- split-precision + squared-norm + self-term fused prep ----------------
// 4 threads per point (slot = tid&3): R10 accounting showed prep+rescore hide
// ~150us at HALF-idle grids (128 blocks / 256 CUs). Each slot converts C/4
// elements, computes COUT/4 rows of the A-GEMV (slots stream DIFFERENT weight
// regions -> no lockstep), sq computed redundantly (slot 0 stores).
__device__ __forceinline__ unsigned bf16_rne(float f) {
    unsigned u = __float_as_uint(f);
    return (u + 0x7fffu + ((u >> 16) & 1u)) >> 16;
}

template<int C, int COUT>
__global__ __launch_bounds__(256)
void prep_fused(const float* __restrict__ x, const float* __restrict__ T,
                const float* __restrict__ b1,
                unsigned short* __restrict__ Xhi,
                unsigned short* __restrict__ Xlo,
                float* __restrict__ sq, float* __restrict__ A) {
    const int tid  = threadIdx.x;
    const int slot = tid & 3;
    const int i    = blockIdx.x * 64 + (tid >> 2);

    float r[C];
    const float4* rp = (const float4*)(x + (size_t)i * C);
#pragma unroll
    for (int c4 = 0; c4 < C / 4; ++c4) {
        float4 f = rp[c4];
        r[4 * c4] = f.x; r[4 * c4 + 1] = f.y; r[4 * c4 + 2] = f.z; r[4 * c4 + 3] = f.w;
    }
    float s = 0.f;
#pragma unroll
    for (int c = 0; c < C; ++c) s = fmaf(r[c], r[c], s);
    if (slot == 0) sq[i] = s;

    constexpr int Q = C / 4;                 // elements converted per slot
#pragma unroll
    for (int cc = 0; cc < Q; cc += 8) {
        const int cb = slot * Q + cc;
        short8 vh, vl;
#pragma unroll
        for (int t = 0; t < 8; ++t) {
            const float f = r[cb + t];
            const unsigned h = bf16_rne(f);
            const float hf = __uint_as_float(h << 16);
            vh[t] = (short)h;
            vl[t] = (short)bf16_rne(f - hf);
        }
        *(short8*)(Xhi + (size_t)i * C + cb) = vh;
        *(short8*)(Xlo + (size_t)i * C + cb) = vl;
    }

    constexpr int OPQ = COUT / 4;            // A-rows per slot
    float* Ap = A + (size_t)i * COUT + slot * OPQ;
#pragma unroll
    for (int oq = 0; oq < OPQ / 4; ++oq) {
        float av[4];
#pragma unroll
        for (int rr = 0; rr < 4; ++rr) {
            const int op = slot * OPQ + oq * 4 + rr;
            const float* tr = T + (size_t)op * (2 * C);
            float a0 = 0.f, a1 = 0.f, a2 = 0.f, a3 = 0.f;
#pragma unroll
            for (int c = 0; c < C; c += 4) {
                a0 = fmaf(tr[c],     r[c],     a0);
                a1 = fmaf(tr[c + 1], r[c + 1], a1);
                a2 = fmaf(tr[c + 2], r[c + 2], a2);
                a3 = fmaf(tr[c + 3], r[c + 3], a3);
            }
            av[rr] = (a0 + a1) + (a2 + a3) + b1[op];
        }
        *(float4*)(Ap + oq * 4) = make_float4(av[0], av[1], av[2], av[3]);
    }
}

// ---------------- weight prep: T[o][c<CIN] = W1a[c][o]-W1b[c][o]; T[o][CIN+c] = W1b[c][o] ----
__global__ void prep_w(const float* __restrict__ W10, const float* __restrict__ W11,
                       const float* __restrict__ W12,
                       float* __restrict__ T0, float* __restrict__ T1,
                       float* __restrict__ T2) {
    int t = blockIdx.x * 256 + threadIdx.x;
    if (t < 4096) {
        int o = t >> 6, c = t & 63;          // T0/T2: 64 ops x 64 cols (CIN=32)
        float wb0 = W10[(32 + (c & 31)) * 64 + o];
        T0[o * 64 + c] = (c < 32) ? (W10[c * 64 + o] - wb0) : wb0;
        float wb2 = W12[(32 + (c & 31)) * 64 + o];
        T2[o * 64 + c] = (c < 32) ? (W12[c * 64 + o] - wb2) : wb2;
        int o1 = t >> 7, c1 = t & 127;       // T1: 32 ops x 128 cols (CIN=64)
        float wb1 = W11[(64 + (c1 & 63)) * 32 + o1];
        T1[o1 * 128 + c1] = (c1 < 64) ? (W11[c1 * 32 + o1] - wb1) : wb1;
    }
}

// sorted ascending top-6 insert via pure min/max network (2 VALU / level).
__device__ __forceinline__ void insert6f(float s, float* dl) {
#pragma unroll
    for (int k = 0; k < 6; ++k) {
        const float a = dl[k];
        dl[k] = fminf(s, a);
        s = fmaxf(s, a);
    }
}

// ---------------- MFMA kNN scan (32x32 tiles, LDS-staged candidates) ----------------
// (unchanged from R9/R10 — verified)
template<int C>
__global__ __launch_bounds__(256, 4)
void knn_scan(const unsigned short* __restrict__ Xhi,
              const unsigned short* __restrict__ Xlo,
              const float* __restrict__ sqv,
              unsigned* __restrict__ plist) {
    constexpr int KT    = C / 16;           // K=16 tiles per product
    constexpr int SR    = C / 4;            // 16B slots per LDS row (hi+lo)
    constexpr int ROWB  = SR * 16;          // 128 / 256 bytes per row
    constexpr int STEPB = 32 * ROWB;        // 4 KB / 8 KB per step buffer
    constexpr int LPT   = STEPB / 16 / 256; // 1 / 2 loads per thread per step
    __shared__ __align__(16) char sm[2 * STEPB];

    const int tid  = threadIdx.x;
    const int w    = __builtin_amdgcn_readfirstlane(tid >> 6);
    const int bid  = blockIdx.x;
    const int swz  = ((bid & 7) << 7) | (bid >> 3);   // 1024 blocks, 128/XCD
    const int b    = swz >> 6;              // batch (2 per XCD)
    const int sp   = (swz >> 4) & 3;        // candidate quarter
    const int qg   = swz & 15;              // query group of 4 tiles
    const int qt   = qg * 4 + w;            // this wave's query tile (32 q)
    const int lane = tid & 63;
    const int q31  = lane & 31;
    const int lh   = lane >> 5;
    const int base = b * NN;
    const int qloc = qt * 32 + q31;         // batch-local query index

    // persistent query fragments
    short8 bh[KT], bl[KT];
#pragma unroll
    for (int kt = 0; kt < KT; ++kt) {
        const size_t off = (size_t)(base + qloc) * C + kt * 16 + lh * 8;
        bh[kt] = *(const short8*)(Xhi + off);
        bl[kt] = *(const short8*)(Xlo + off);
    }

    float dl[6];
#pragma unroll
    for (int k = 0; k < 6; ++k) dl[k] = 1e30f;

    const int jbeg   = sp * (NN / 4);
    const int selfjb = qt * 32;             // only step that can contain self

    // staging source pointers: thread's LDS slot sidx -> (row, slot);
    // content = SRC[row][slot ^ (row&(SR-1))] (XOR involution; reader undoes it)
    const unsigned short* src[LPT];
#pragma unroll
    for (int l = 0; l < LPT; ++l) {
        const int sidx = tid + l * 256;
        const int row  = sidx / SR;
        const int slot = sidx % SR;
        const int u    = slot ^ (row & (SR - 1));
        const unsigned short* bp = (u < SR / 2) ? Xhi : Xlo;
        src[l] = bp + (size_t)(base + jbeg + row) * C + (u & (SR / 2 - 1)) * 8;
    }

    // per-lane ds-read constants
    const int m       = q31 & (SR - 1);
    const int rowbase = q31 * ROWB;
    const float* sqp  = sqv + base + jbeg + lh * 4;
    float4 s4[4];

#define STAGE(BUF) do {                                                        \
    _Pragma("unroll")                                                          \
    for (int l = 0; l < LPT; ++l) {                                            \
        __builtin_amdgcn_global_load_lds(                                      \
            (const __attribute__((address_space(1))) void*)src[l],             \
            (__attribute__((address_space(3))) void*)                          \
                (sm + (BUF) * STEPB + l * 4096 + w * 1024),                    \
            16, 0, 0);                                                         \
        src[l] += 32 * C;                                                      \
    }                                                                          \
} while (0)

#define COMPUTE(BUF, JB) do {                                                  \
    const char* smc = sm + (BUF) * STEPB;                                      \
    f32x16 acc = {0.f};                                                        \
    _Pragma("unroll")                                                          \
    for (int kt = 0; kt < KT; ++kt) {                                          \
        const int uh = kt * 2 + lh;                                            \
        const int ul = 2 * KT + kt * 2 + lh;                                   \
        const short8 ah = *(const short8*)(smc + rowbase + ((uh ^ m) << 4));   \
        const short8 al = *(const short8*)(smc + rowbase + ((ul ^ m) << 4));   \
        acc = __builtin_amdgcn_mfma_f32_32x32x16_bf16(ah, bh[kt], acc, 0, 0, 0); \
        acc = __builtin_amdgcn_mfma_f32_32x32x16_bf16(ah, bl[kt], acc, 0, 0, 0); \
        acc = __builtin_amdgcn_mfma_f32_32x32x16_bf16(al, bh[kt], acc, 0, 0, 0); \
    }                                                                          \
    const unsigned ebase = (unsigned)(((JB) - jbeg) >> 1);   /* step*16 */     \
    const bool selfstep = ((JB) == selfjb);                                    \
    _Pragma("unroll")                                                          \
    for (int g4 = 0; g4 < 4; ++g4) {                                           \
        _Pragma("unroll")                                                      \
        for (int rr = 0; rr < 4; ++rr) {                                       \
            const int r = g4 * 4 + rr;                                         \
            float sc = fmaf(-2.f, acc[r],                                      \
                rr == 0 ? s4[g4].x : rr == 1 ? s4[g4].y :                      \
                rr == 2 ? s4[g4].z : s4[g4].w);                                \
            sc = __uint_as_float((__float_as_uint(sc) & 0xFFFFFF00u) |         \
                                 (ebase + (unsigned)((r & 3) + 4 * (r >> 2)))); \
            if (selfstep) {                                                    \
                const int rowr = (r & 3) + 8 * (r >> 2) + 4 * lh;              \
                sc = (rowr == q31) ? 1e30f : sc;                               \
            }                                                                  \
            insert6f(sc, dl);                                                  \
        }                                                                      \
    }                                                                          \
} while (0)

    STAGE(0);                               // prologue: step 0 in flight
    int jb = jbeg, cur = 0;
#pragma unroll 1
    for (int st = 0; st < 15; ++st) {
        __builtin_amdgcn_s_barrier();       // WAR: all waves done reading buf cur^1
#pragma unroll
        for (int g4 = 0; g4 < 4; ++g4) s4[g4] = *(const float4*)(sqp + g4 * 8);
        asm volatile("" ::: "memory");      // pin: sq loads issue BEFORE stage
        STAGE(cur ^ 1);                     // step st+1 in flight
        if constexpr (C == 32) asm volatile("s_waitcnt vmcnt(1)" ::: "memory");
        else                   asm volatile("s_waitcnt vmcnt(2)" ::: "memory");
        __builtin_amdgcn_s_barrier();       // RAW: all waves' step-st data landed
        COMPUTE(cur, jb);
        jb += 32; sqp += 32; cur ^= 1;
    }
    {   // epilogue: last step, drain
        __builtin_amdgcn_s_barrier();
#pragma unroll
        for (int g4 = 0; g4 < 4; ++g4) s4[g4] = *(const float4*)(sqp + g4 * 8);
        asm volatile("s_waitcnt vmcnt(0)" ::: "memory");
        __builtin_amdgcn_s_barrier();
        COMPUTE(cur, jb);
    }
#undef STAGE
#undef COMPUTE

    // write this lane's sorted sublist as sortable-transformed u32 keys
    unsigned* o = plist + (size_t)(base + qloc) * 48 + (sp * 2 + lh) * 6;
#pragma unroll
    for (int k = 0; k < 6; ++k) {
        const unsigned bits = __float_as_uint(dl[k]);
        o[k] = bits ^ ((bits & 0x80000000u) ? 0xFFFFFFFFu : 0x80000000u);
    }
}

// ---------------- exact rescore: 2 threads/query ----------------
// slot = gi&1 (lane-adjacent pair). Each slot merges ITS 4 sublists (sp 0,1
// vs 2,3 -> disjoint candidate ranges) to approx top-7 (cushion 1 over the
// per-half exact top-6), rescores the 7 in exact fp32, keeps exact top-6,
// exchanges with partner via 2x32b shfl_xor, and both compute the identical
// final top-6 of the 12 (keys unique via jloc). Each slot writes 3 outputs.
// Grid 2x R10's (256 blocks), XCD-swizzled for gather L2 locality.
template<int C>
__global__ __launch_bounds__(256)
void rescore(const float* __restrict__ x, const float* __restrict__ sqv,
             const unsigned* __restrict__ plist, int* __restrict__ nbr) {
    const int bid  = blockIdx.x;
    const int bsw  = ((bid & 7) << 5) | (bid >> 3);   // 256 blocks, bijective
    const int gi   = bsw * 256 + threadIdx.x;
    const int i    = gi >> 1;
    const int slot = gi & 1;

    const unsigned* pr = plist + (size_t)i * 48 + slot * 24;

    unsigned long long best[7];
#pragma unroll
    for (int k = 0; k < 7; ++k) best[k] = ~0ull;
    for (int z4 = 0; z4 < 4; ++z4) {
        const unsigned* p = pr + z4 * 6;
        const unsigned zg = (unsigned)(slot * 4 + z4);
        for (int e = 0; e < 6; ++e) {
            unsigned long long v = ((unsigned long long)p[e] << 3) | zg;
            if (v >= best[6]) break;      // sublist ascending
            best[6] = v;
#pragma unroll
            for (int k = 5; k >= 0; --k) {
                if (best[k + 1] < best[k]) {
                    unsigned long long t = best[k]; best[k] = best[k + 1]; best[k + 1] = t;
                }
            }
        }
    }

    const int base = i & ~(NN - 1);
    float4 qv[C / 4];
    const float4* qp = (const float4*)(x + (size_t)i * C);
#pragma unroll
    for (int t = 0; t < C / 4; ++t) qv[t] = qp[t];

    unsigned long long out6[6];
#pragma unroll
    for (int k = 0; k < 6; ++k) out6[k] = ~0ull;

    for (int m = 0; m < 7; ++m) {
        const unsigned u32k = (unsigned)(best[m] >> 3);
        const int z = (int)(best[m] & 7ull);
        const unsigned orig = (u32k & 0x80000000u) ? (u32k ^ 0x80000000u) : ~u32k;
        const int e = (int)(orig & 255u);
        const int idx = e & 15;
        const int jloc = (z >> 1) * (NN / 4) + (e >> 4) * 32 +
                         (idx & 3) + 8 * (idx >> 2) + (z & 1) * 4;

        const float4* cp = (const float4*)(x + (size_t)(base + jloc) * C);
        float d0 = 0.f, d1 = 0.f, d2 = 0.f, d3 = 0.f;
#pragma unroll
        for (int t = 0; t < C / 4; ++t) {
            float4 a = cp[t];
            d0 = fmaf(a.x, qv[t].x, d0);
            d1 = fmaf(a.y, qv[t].y, d1);
            d2 = fmaf(a.z, qv[t].z, d2);
            d3 = fmaf(a.w, qv[t].w, d3);
        }
        const float s = fmaf(-2.f, (d0 + d1) + (d2 + d3), sqv[base + jloc]);
        unsigned u = __float_as_uint(s);
        u ^= (u & 0x80000000u) ? 0xFFFFFFFFu : 0x80000000u;
        unsigned long long key = ((unsigned long long)u << 11) | (unsigned)jloc;
#pragma unroll
        for (int k = 0; k < 6; ++k) {
            const unsigned long long ok = out6[k];
            const bool c = key < ok;
            out6[k] = c ? key : ok;
            key     = c ? ok  : key;
        }
    }

    // exchange per-half exact top-6 with partner; merge to final top-6
    unsigned long long fin[6];
#pragma unroll
    for (int k = 0; k < 6; ++k) fin[k] = out6[k];
#pragma unroll
    for (int k = 0; k < 6; ++k) {
        const unsigned long long v = out6[k];
        const unsigned lo = __shfl_xor((unsigned)v, 1);
        const unsigned hi = __shfl_xor((unsigned)(v >> 32), 1);
        unsigned long long key = ((unsigned long long)hi << 32) | lo;
#pragma unroll
        for (int q = 0; q < 6; ++q) {
            const unsigned long long ok = fin[q];
            const bool c = key < ok;
            fin[q] = c ? key : ok;
            key    = c ? ok  : key;
        }
    }
#pragma unroll
    for (int k = 0; k < 3; ++k)
        nbr[i * KNB + slot * 3 + k] = base + (int)(fin[slot * 3 + k] & 2047ull);
}

// ---------------- edge MLP kernel (output-split + wave op-stagger + XCD swizzle) ----------------
// (unchanged from R10 — verified: 69 -> 62us, FETCH 16.5 -> 6.65MB)
template<int CIN, int COUT, bool RESID, int MINW>
__global__ __launch_bounds__(768, MINW)
void mlp_kernel(const float* __restrict__ xin, const int* __restrict__ nbr,
                const float* __restrict__ A,  const float* __restrict__ T,
                const float* __restrict__ W2, const float* __restrict__ b2,
                const float* __restrict__ resid, float* __restrict__ out) {
    constexpr int HALF = COUT / 2;
    constexpr int NQ   = COUT / 4;
    constexpr int RS = HALF + 4;
    __shared__ float Buf[2][3][64][RS];

    const int tid  = threadIdx.x;
    const int lane = tid & 63;
    const int wv   = __builtin_amdgcn_readfirstlane(tid >> 6);  // 0..11
    const int oh   = wv / 6;                                    // output half
    const int w6   = wv % 6;                                    // neighbor
    const int bid  = blockIdx.x;
    const int bsw  = ((bid & 7) << 6) | (bid >> 3);             // XCD swizzle, 512 blocks
    const int i    = bsw * 64 + lane;
    const int j    = nbr[i * KNB + w6];

    float xj[CIN];
    {
        const float4* jp = (const float4*)(xin + (size_t)j * CIN);
#pragma unroll
        for (int c4 = 0; c4 < CIN / 4; ++c4) {
            float4 f = jp[c4];
            xj[4 * c4] = f.x; xj[4 * c4 + 1] = f.y;
            xj[4 * c4 + 2] = f.z; xj[4 * c4 + 3] = f.w;
        }
    }

    float uacc[HALF];
#pragma unroll
    for (int o = 0; o < HALF; ++o) uacc[o] = 0.f;

    cfloat* W1c = (cfloat*)(uintptr_t)T;     // use cols CIN..2CIN (W1b^T)
    cfloat* W2c = (cfloat*)(uintptr_t)W2;
    const float* Ap = A + (size_t)i * COUT;

    const int qofs = (wv * 3) & (NQ - 1);    // wave-staggered op start

#pragma unroll 2
    for (int qi = 0; qi < NQ; ++qi) {
        const int oq = (qi + qofs) & (NQ - 1);
        const float4 a4 = *(const float4*)(Ap + 4 * oq);
#pragma unroll
        for (int rr = 0; rr < 4; ++rr) {
            const int op = oq * 4 + rr;
            cfloat* w1r = W1c + (size_t)op * (2 * CIN) + CIN;
            float h0 = 0.f, h1 = 0.f, h2 = 0.f, h3 = 0.f;
#pragma unroll
            for (int c = 0; c < CIN; c += 4) {
                h0 = fmaf(w1r[c],     xj[c],     h0);
                h1 = fmaf(w1r[c + 1], xj[c + 1], h1);
                h2 = fmaf(w1r[c + 2], xj[c + 2], h2);
                h3 = fmaf(w1r[c + 3], xj[c + 3], h3);
            }
            const float aop = rr == 0 ? a4.x : rr == 1 ? a4.y : rr == 2 ? a4.z : a4.w;
            const float h = fmaxf((h0 + h1) + (h2 + h3) + aop, 0.f);
            cfloat* w2r = W2c + (size_t)op * COUT + oh * HALF;
#pragma unroll
            for (int o = 0; o < HALF; ++o)
                uacc[o] = fmaf(w2r[o], h, uacc[o]);
        }
    }

    // per-half 6 -> 1 max tree over neighbor waves
    if (w6 >= 3) {
#pragma unroll
        for (int o = 0; o < HALF; ++o) Buf[oh][w6 - 3][lane][o] = uacc[o];
    }
    __syncthreads();
    if (w6 < 3) {
#pragma unroll
        for (int o = 0; o < HALF; ++o) uacc[o] = fmaxf(uacc[o], Buf[oh][w6][lane][o]);
    }
    __syncthreads();
    if (w6 == 1 || w6 == 2) {
#pragma unroll
        for (int o = 0; o < HALF; ++o) Buf[oh][w6][lane][o] = uacc[o];
    }
    __syncthreads();
    if (w6 == 0) {
        float* po = out + (size_t)i * COUT + oh * HALF;
        const float* b2p = b2 + oh * HALF;
#pragma unroll
        for (int o = 0; o < HALF; ++o) {
            float v = fmaxf(uacc[o], fmaxf(Buf[oh][1][lane][o], Buf[oh][2][lane][o])) + b2p[o];
            if (RESID) v += resid[(size_t)i * COUT + oh * HALF + o];
            po[o] = fmaxf(v, 0.f);
        }
    }
}

extern "C" void kernel_launch(void* const* d_in, const int* in_sizes, int n_in,
                              void* d_out, int out_size, void* d_ws, size_t ws_size,
                              hipStream_t stream) {
    const float* x    = (const float*)d_in[0];
    const float* W1_0 = (const float*)d_in[2];
    const float* b1_0 = (const float*)d_in[3];
    const float* W2_0 = (const float*)d_in[4];
    const float* b2_0 = (const float*)d_in[5];
    const float* W1_1 = (const float*)d_in[6];
    const float* b1_1 = (const float*)d_in[7];
    const float* W2_1 = (const float*)d_in[8];
    const float* b2_1 = (const float*)d_in[9];
    const float* W1_2 = (const float*)d_in[10];
    const float* b1_2 = (const float*)d_in[11];
    const float* W2_2 = (const float*)d_in[12];
    const float* b2_2 = (const float*)d_in[13];
    float* outp = (float*)d_out;

    // workspace layout
    unsigned* plist = (unsigned*)d_ws;                            // NPTS*48 u32
    float* x0  = (float*)(plist + (size_t)NPTS * 48);             // 32768 x 64
    float* x1  = x0 + (size_t)NPTS * 64;                          // 32768 x 32
    float* sqb = x1 + (size_t)NPTS * 32;                          // 32768
    float* T0  = sqb + NPTS;                                      // 64 x 64
    float* T1  = T0 + 4096;                                       // 32 x 128
    float* T2  = T1 + 4096;                                       // 64 x 64
    unsigned short* Xhi = (unsigned short*)(T2 + 4096);           // 32768 x 64 u16
    unsigned short* Xlo = Xhi + (size_t)NPTS * 64;                // 32768 x 64 u16
    int* nbr = (int*)(Xlo + (size_t)NPTS * 64);                   // 32768 x 6
    float* Abuf = (float*)(nbr + (size_t)NPTS * KNB);             // 32768 x 64

    const int fgrid  = NPTS / 64;       // prep: 4 thr/point, 512 blocks
    const int rgrid  = NPTS * 2 / 256;  // rescore: 2 thr/query, 256 blocks
    const int scgrid = 1024;            // 4096 waves of 32q x 512c
    const int pgrid  = NPTS / 64;       // 512 blocks x 768 thr

    prep_w<<<16, 256, 0, stream>>>(W1_0, W1_1, W1_2, T0, T1, T2);

    // ---- layer 0: x (32) -> x0 (64), relu ----
    prep_fused<32, 64><<<fgrid, 256, 0, stream>>>(x, T0, b1_0, Xhi, Xlo, sqb, Abuf);
    knn_scan<32><<<scgrid, 256, 0, stream>>>(Xhi, Xlo, sqb, plist);
    rescore<32><<<rgrid, 256, 0, stream>>>(x, sqb, plist, nbr);
    mlp_kernel<32, 64, false, 5><<<pgrid, 768, 0, stream>>>(x, nbr, Abuf, T0, W2_0, b2_0, nullptr, x0);

    // ---- layer 1: x0 (64) -> x1 (32), relu ----
    prep_fused<64, 32><<<fgrid, 256, 0, stream>>>(x0, T1, b1_1, Xhi, Xlo, sqb, Abuf);
    knn_scan<64><<<scgrid, 256, 0, stream>>>(Xhi, Xlo, sqb, plist);
    rescore<64><<<rgrid, 256, 0, stream>>>(x0, sqb, plist, nbr);
    mlp_kernel<64, 32, false, 4><<<pgrid, 768, 0, stream>>>(x0, nbr, Abuf, T1, W2_1, b2_1, nullptr, x1);

    // ---- layer 2: x1 (32) -> out (64), +x0 residual, relu ----
    prep_fused<32, 64><<<fgrid, 256, 0, stream>>>(x1, T2, b1_2, Xhi, Xlo, sqb, Abuf);
    knn_scan<32><<<scgrid, 256, 0, stream>>>(Xhi, Xlo, sqb, plist);
    rescore<32><<<rgrid, 256, 0, stream>>>(x1, sqb, plist, nbr);
    mlp_kernel<32, 64, true, 5><<<pgrid, 768, 0, stream>>>(x1, nbr, Abuf, T2, W2_2, b2_2, x0, outp);
}

// Round 12
// 506.004 us; speedup vs baseline: 1.2434x; 1.0376x over previous
//
#include <hip/hip_runtime.h>

#define NB   16
#define NN   2048
#define NPTS (NB * NN)
#define KNB  6

typedef __attribute__((ext_vector_type(8))) short short8;
typedef __attribute__((ext_vector_type(2))) float f32x2;
typedef __attribute__((ext_vector_type(4))) float f32x4;
typedef __attribute__((ext_vector_type(16))) float f32x16;
typedef const __attribute__((address_space(4))) float cfloat;
typedef const __attribute__((address_space(4))) f32x2 cf32x2;

// ---------------- split-precision + squared-norm + self-term fused prep ----------------
// 4 threads per point (slot = tid&3); verified R11.
__device__ __forceinline__ unsigned bf16_rne(float f) {
    unsigned u = __float_as_uint(f);
    return (u + 0x7fffu + ((u >> 16) & 1u)) >> 16;
}

template<int C, int COUT>
__global__ __launch_bounds__(256)
void prep_fused(const float* __restrict__ x, const float* __restrict__ T,
                const float* __restrict__ b1,
                unsigned short* __restrict__ Xhi,
                unsigned short* __restrict__ Xlo,
                float* __restrict__ sq, float* __restrict__ A) {
    const int tid  = threadIdx.x;
    const int slot = tid & 3;
    const int i    = blockIdx.x * 64 + (tid >> 2);

    float r[C];
    const float4* rp = (const float4*)(x + (size_t)i * C);
#pragma unroll
    for (int c4 = 0; c4 < C / 4; ++c4) {
        float4 f = rp[c4];
        r[4 * c4] = f.x; r[4 * c4 + 1] = f.y; r[4 * c4 + 2] = f.z; r[4 * c4 + 3] = f.w;
    }
    float s = 0.f;
#pragma unroll
    for (int c = 0; c < C; ++c) s = fmaf(r[c], r[c], s);
    if (slot == 0) sq[i] = s;

    constexpr int Q = C / 4;                 // elements converted per slot
#pragma unroll
    for (int cc = 0; cc < Q; cc += 8) {
        const int cb = slot * Q + cc;
        short8 vh, vl;
#pragma unroll
        for (int t = 0; t < 8; ++t) {
            const float f = r[cb + t];
            const unsigned h = bf16_rne(f);
            const float hf = __uint_as_float(h << 16);
            vh[t] = (short)h;
            vl[t] = (short)bf16_rne(f - hf);
        }
        *(short8*)(Xhi + (size_t)i * C + cb) = vh;
        *(short8*)(Xlo + (size_t)i * C + cb) = vl;
    }

    constexpr int OPQ = COUT / 4;            // A-rows per slot
    float* Ap = A + (size_t)i * COUT + slot * OPQ;
#pragma unroll
    for (int oq = 0; oq < OPQ / 4; ++oq) {
        float av[4];
#pragma unroll
        for (int rr = 0; rr < 4; ++rr) {
            const int op = slot * OPQ + oq * 4 + rr;
            const float* tr = T + (size_t)op * (2 * C);
            float a0 = 0.f, a1 = 0.f, a2 = 0.f, a3 = 0.f;
#pragma unroll
            for (int c = 0; c < C; c += 4) {
                a0 = fmaf(tr[c],     r[c],     a0);
                a1 = fmaf(tr[c + 1], r[c + 1], a1);
                a2 = fmaf(tr[c + 2], r[c + 2], a2);
                a3 = fmaf(tr[c + 3], r[c + 3], a3);
            }
            av[rr] = (a0 + a1) + (a2 + a3) + b1[op];
        }
        *(float4*)(Ap + oq * 4) = make_float4(av[0], av[1], av[2], av[3]);
    }
}

// ---------------- weight prep: T[o][c<CIN] = W1a[c][o]-W1b[c][o]; T[o][CIN+c] = W1b[c][o] ----
__global__ void prep_w(const float* __restrict__ W10, const float* __restrict__ W11,
                       const float* __restrict__ W12,
                       float* __restrict__ T0, float* __restrict__ T1,
                       float* __restrict__ T2) {
    int t = blockIdx.x * 256 + threadIdx.x;
    if (t < 4096) {
        int o = t >> 6, c = t & 63;          // T0/T2: 64 ops x 64 cols (CIN=32)
        float wb0 = W10[(32 + (c & 31)) * 64 + o];
        T0[o * 64 + c] = (c < 32) ? (W10[c * 64 + o] - wb0) : wb0;
        float wb2 = W12[(32 + (c & 31)) * 64 + o];
        T2[o * 64 + c] = (c < 32) ? (W12[c * 64 + o] - wb2) : wb2;
        int o1 = t >> 7, c1 = t & 127;       // T1: 32 ops x 128 cols (CIN=64)
        float wb1 = W11[(64 + (c1 & 63)) * 32 + o1];
        T1[o1 * 128 + c1] = (c1 < 64) ? (W11[c1 * 32 + o1] - wb1) : wb1;
    }
}

// sorted ascending top-6 insert via pure min/max network (2 VALU / level).
__device__ __forceinline__ void insert6f(float s, float* dl) {
#pragma unroll
    for (int k = 0; k < 6; ++k) {
        const float a = dl[k];
        dl[k] = fminf(s, a);
        s = fmaxf(s, a);
    }
}

// ---------------- MFMA kNN scan (32x32 tiles, LDS-staged candidates) ----------------
// (unchanged from R9/R10 — verified)
template<int C>
__global__ __launch_bounds__(256, 4)
void knn_scan(const unsigned short* __restrict__ Xhi,
              const unsigned short* __restrict__ Xlo,
              const float* __restrict__ sqv,
              unsigned* __restrict__ plist) {
    constexpr int KT    = C / 16;           // K=16 tiles per product
    constexpr int SR    = C / 4;            // 16B slots per LDS row (hi+lo)
    constexpr int ROWB  = SR * 16;          // 128 / 256 bytes per row
    constexpr int STEPB = 32 * ROWB;        // 4 KB / 8 KB per step buffer
    constexpr int LPT   = STEPB / 16 / 256; // 1 / 2 loads per thread per step
    __shared__ __align__(16) char sm[2 * STEPB];

    const int tid  = threadIdx.x;
    const int w    = __builtin_amdgcn_readfirstlane(tid >> 6);
    const int bid  = blockIdx.x;
    const int swz  = ((bid & 7) << 7) | (bid >> 3);   // 1024 blocks, 128/XCD
    const int b    = swz >> 6;              // batch (2 per XCD)
    const int sp   = (swz >> 4) & 3;        // candidate quarter
    const int qg   = swz & 15;              // query group of 4 tiles
    const int qt   = qg * 4 + w;            // this wave's query tile (32 q)
    const int lane = tid & 63;
    const int q31  = lane & 31;
    const int lh   = lane >> 5;
    const int base = b * NN;
    const int qloc = qt * 32 + q31;         // batch-local query index

    // persistent query fragments
    short8 bh[KT], bl[KT];
#pragma unroll
    for (int kt = 0; kt < KT; ++kt) {
        const size_t off = (size_t)(base + qloc) * C + kt * 16 + lh * 8;
        bh[kt] = *(const short8*)(Xhi + off);
        bl[kt] = *(const short8*)(Xlo + off);
    }

    float dl[6];
#pragma unroll
    for (int k = 0; k < 6; ++k) dl[k] = 1e30f;

    const int jbeg   = sp * (NN / 4);
    const int selfjb = qt * 32;             // only step that can contain self

    // staging source pointers: thread's LDS slot sidx -> (row, slot);
    // content = SRC[row][slot ^ (row&(SR-1))] (XOR involution; reader undoes it)
    const unsigned short* src[LPT];
#pragma unroll
    for (int l = 0; l < LPT; ++l) {
        const int sidx = tid + l * 256;
        const int row  = sidx / SR;
        const int slot = sidx % SR;
        const int u    = slot ^ (row & (SR - 1));
        const unsigned short* bp = (u < SR / 2) ? Xhi : Xlo;
        src[l] = bp + (size_t)(base + jbeg + row) * C + (u & (SR / 2 - 1)) * 8;
    }

    // per-lane ds-read constants
    const int m       = q31 & (SR - 1);
    const int rowbase = q31 * ROWB;
    const float* sqp  = sqv + base + jbeg + lh * 4;
    float4 s4[4];

#define STAGE(BUF) do {                                                        \
    _Pragma("unroll")                                                          \
    for (int l = 0; l < LPT; ++l) {                                            \
        __builtin_amdgcn_global_load_lds(                                      \
            (const __attribute__((address_space(1))) void*)src[l],             \
            (__attribute__((address_space(3))) void*)                          \
                (sm + (BUF) * STEPB + l * 4096 + w * 1024),                    \
            16, 0, 0);                                                         \
        src[l] += 32 * C;                                                      \
    }                                                                          \
} while (0)

#define COMPUTE(BUF, JB) do {                                                  \
    const char* smc = sm + (BUF) * STEPB;                                      \
    f32x16 acc = {0.f};                                                        \
    _Pragma("unroll")                                                          \
    for (int kt = 0; kt < KT; ++kt) {                                          \
        const int uh = kt * 2 + lh;                                            \
        const int ul = 2 * KT + kt * 2 + lh;                                   \
        const short8 ah = *(const short8*)(smc + rowbase + ((uh ^ m) << 4));   \
        const short8 al = *(const short8*)(smc + rowbase + ((ul ^ m) << 4));   \
        acc = __builtin_amdgcn_mfma_f32_32x32x16_bf16(ah, bh[kt], acc, 0, 0, 0); \
        acc = __builtin_amdgcn_mfma_f32_32x32x16_bf16(ah, bl[kt], acc, 0, 0, 0); \
        acc = __builtin_amdgcn_mfma_f32_32x32x16_bf16(al, bh[kt], acc, 0, 0, 0); \
    }                                                                          \
    const unsigned ebase = (unsigned)(((JB) - jbeg) >> 1);   /* step*16 */     \
    const bool selfstep = ((JB) == selfjb);                                    \
    _Pragma("unroll")                                                          \
    for (int g4 = 0; g4 < 4; ++g4) {                                           \
        _Pragma("unroll")                                                      \
        for (int rr = 0; rr < 4; ++rr) {                                       \
            const int r = g4 * 4 + rr;                                         \
            float sc = fmaf(-2.f, acc[r],                                      \
                rr == 0 ? s4[g4].x : rr == 1 ? s4[g4].y :                      \
                rr == 2 ? s4[g4].z : s4[g4].w);                                \
            sc = __uint_as_float((__float_as_uint(sc) & 0xFFFFFF00u) |         \
                                 (ebase + (unsigned)((r & 3) + 4 * (r >> 2)))); \
            if (selfstep) {                                                    \
                const int rowr = (r & 3) + 8 * (r >> 2) + 4 * lh;              \
                sc = (rowr == q31) ? 1e30f : sc;                               \
            }                                                                  \
            insert6f(sc, dl);                                                  \
        }                                                                      \
    }                                                                          \
} while (0)

    STAGE(0);                               // prologue: step 0 in flight
    int jb = jbeg, cur = 0;
#pragma unroll 1
    for (int st = 0; st < 15; ++st) {
        __builtin_amdgcn_s_barrier();       // WAR: all waves done reading buf cur^1
#pragma unroll
        for (int g4 = 0; g4 < 4; ++g4) s4[g4] = *(const float4*)(sqp + g4 * 8);
        asm volatile("" ::: "memory");      // pin: sq loads issue BEFORE stage
        STAGE(cur ^ 1);                     // step st+1 in flight
        if constexpr (C == 32) asm volatile("s_waitcnt vmcnt(1)" ::: "memory");
        else                   asm volatile("s_waitcnt vmcnt(2)" ::: "memory");
        __builtin_amdgcn_s_barrier();       // RAW: all waves' step-st data landed
        COMPUTE(cur, jb);
        jb += 32; sqp += 32; cur ^= 1;
    }
    {   // epilogue: last step, drain
        __builtin_amdgcn_s_barrier();
#pragma unroll
        for (int g4 = 0; g4 < 4; ++g4) s4[g4] = *(const float4*)(sqp + g4 * 8);
        asm volatile("s_waitcnt vmcnt(0)" ::: "memory");
        __builtin_amdgcn_s_barrier();
        COMPUTE(cur, jb);
    }
#undef STAGE
#undef COMPUTE

    // write this lane's sorted sublist as sortable-transformed u32 keys
    unsigned* o = plist + (size_t)(base + qloc) * 48 + (sp * 2 + lh) * 6;
#pragma unroll
    for (int k = 0; k < 6; ++k) {
        const unsigned bits = __float_as_uint(dl[k]);
        o[k] = bits ^ ((bits & 0x80000000u) ? 0xFFFFFFFFu : 0x80000000u);
    }
}

// ---------------- exact rescore: 2 threads/query (verified R11) ----------------
template<int C>
__global__ __launch_bounds__(256)
void rescore(const float* __restrict__ x, const float* __restrict__ sqv,
             const unsigned* __restrict__ plist, int* __restrict__ nbr) {
    const int bid  = blockIdx.x;
    const int bsw  = ((bid & 7) << 5) | (bid >> 3);   // 256 blocks, bijective
    const int gi   = bsw * 256 + threadIdx.x;
    const int i    = gi >> 1;
    const int slot = gi & 1;

    const unsigned* pr = plist + (size_t)i * 48 + slot * 24;

    unsigned long long best[7];
#pragma unroll
    for (int k = 0; k < 7; ++k) best[k] = ~0ull;
    for (int z4 = 0; z4 < 4; ++z4) {
        const unsigned* p = pr + z4 * 6;
        const unsigned zg = (unsigned)(slot * 4 + z4);
        for (int e = 0; e < 6; ++e) {
            unsigned long long v = ((unsigned long long)p[e] << 3) | zg;
            if (v >= best[6]) break;      // sublist ascending
            best[6] = v;
#pragma unroll
            for (int k = 5; k >= 0; --k) {
                if (best[k + 1] < best[k]) {
                    unsigned long long t = best[k]; best[k] = best[k + 1]; best[k + 1] = t;
                }
            }
        }
    }

    const int base = i & ~(NN - 1);
    float4 qv[C / 4];
    const float4* qp = (const float4*)(x + (size_t)i * C);
#pragma unroll
    for (int t = 0; t < C / 4; ++t) qv[t] = qp[t];

    unsigned long long out6[6];
#pragma unroll
    for (int k = 0; k < 6; ++k) out6[k] = ~0ull;

    for (int m = 0; m < 7; ++m) {
        const unsigned u32k = (unsigned)(best[m] >> 3);
        const int z = (int)(best[m] & 7ull);
        const unsigned orig = (u32k & 0x80000000u) ? (u32k ^ 0x80000000u) : ~u32k;
        const int e = (int)(orig & 255u);
        const int idx = e & 15;
        const int jloc = (z >> 1) * (NN / 4) + (e >> 4) * 32 +
                         (idx & 3) + 8 * (idx >> 2) + (z & 1) * 4;

        const float4* cp = (const float4*)(x + (size_t)(base + jloc) * C);
        float d0 = 0.f, d1 = 0.f, d2 = 0.f, d3 = 0.f;
#pragma unroll
        for (int t = 0; t < C / 4; ++t) {
            float4 a = cp[t];
            d0 = fmaf(a.x, qv[t].x, d0);
            d1 = fmaf(a.y, qv[t].y, d1);
            d2 = fmaf(a.z, qv[t].z, d2);
            d3 = fmaf(a.w, qv[t].w, d3);
        }
        const float s = fmaf(-2.f, (d0 + d1) + (d2 + d3), sqv[base + jloc]);
        unsigned u = __float_as_uint(s);
        u ^= (u & 0x80000000u) ? 0xFFFFFFFFu : 0x80000000u;
        unsigned long long key = ((unsigned long long)u << 11) | (unsigned)jloc;
#pragma unroll
        for (int k = 0; k < 6; ++k) {
            const unsigned long long ok = out6[k];
            const bool c = key < ok;
            out6[k] = c ? key : ok;
            key     = c ? ok  : key;
        }
    }

    // exchange per-half exact top-6 with partner; merge to final top-6
    unsigned long long fin[6];
#pragma unroll
    for (int k = 0; k < 6; ++k) fin[k] = out6[k];
#pragma unroll
    for (int k = 0; k < 6; ++k) {
        const unsigned long long v = out6[k];
        const unsigned lo = __shfl_xor((unsigned)v, 1);
        const unsigned hi = __shfl_xor((unsigned)(v >> 32), 1);
        unsigned long long key = ((unsigned long long)hi << 32) | lo;
#pragma unroll
        for (int q = 0; q < 6; ++q) {
            const unsigned long long ok = fin[q];
            const bool c = key < ok;
            fin[q] = c ? key : ok;
            key    = c ? ok  : key;
        }
    }
#pragma unroll
    for (int k = 0; k < 3; ++k)
        nbr[i * KNB + slot * 3 + k] = base + (int)(fin[slot * 3 + k] & 2047ull);
}

// ---------------- edge MLP kernel (packed fp32 math, output-split, stagger, XCD swizzle) ----------------
// R11 PMC: VALUBusy 38%, VGPR 48, no spill -- the wall is VALU ISSUE COUNT
// (per op: CIN + HALF scalar FMAs = ~128cy). Halve it with v_pk_fma_f32:
// xj packed as f32x2 pairs, dual packed h-accumulators, uacc as f32x2 pairs,
// hv = {h,h} broadcast for the W2 update. Weights stay on the scalar pipe
// (R6's spill came from LDS staging, not packing). All max-tree indices
// remain compile-time constant (rule #20). Structure otherwise identical to
// the verified R10/R11 kernel (output-split halves, op-stagger, XCD swizzle).
template<int CIN, int COUT, bool RESID, int MINW>
__global__ __launch_bounds__(768, MINW)
void mlp_kernel(const float* __restrict__ xin, const int* __restrict__ nbr,
                const float* __restrict__ A,  const float* __restrict__ T,
                const float* __restrict__ W2, const float* __restrict__ b2,
                const float* __restrict__ resid, float* __restrict__ out) {
    constexpr int HALF = COUT / 2;
    constexpr int NQ   = COUT / 4;
    constexpr int RS = HALF + 4;
    __shared__ float Buf[2][3][64][RS];

    const int tid  = threadIdx.x;
    const int lane = tid & 63;
    const int wv   = __builtin_amdgcn_readfirstlane(tid >> 6);  // 0..11
    const int oh   = wv / 6;                                    // output half
    const int w6   = wv % 6;                                    // neighbor
    const int bid  = blockIdx.x;
    const int bsw  = ((bid & 7) << 6) | (bid >> 3);             // XCD swizzle, 512 blocks
    const int i    = bsw * 64 + lane;
    const int j    = nbr[i * KNB + w6];

    f32x2 xp[CIN / 2];
    {
        const float4* jp = (const float4*)(xin + (size_t)j * CIN);
#pragma unroll
        for (int c4 = 0; c4 < CIN / 4; ++c4) {
            float4 f = jp[c4];
            xp[2 * c4]     = (f32x2){f.x, f.y};
            xp[2 * c4 + 1] = (f32x2){f.z, f.w};
        }
    }

    f32x2 uacc[HALF / 2];
#pragma unroll
    for (int o = 0; o < HALF / 2; ++o) uacc[o] = (f32x2){0.f, 0.f};

    cfloat* W1c = (cfloat*)(uintptr_t)T;     // use cols CIN..2CIN (W1b^T)
    cfloat* W2c = (cfloat*)(uintptr_t)W2;
    const float* Ap = A + (size_t)i * COUT;

    const int qofs = (wv * 3) & (NQ - 1);    // wave-staggered op start

#pragma unroll 2
    for (int qi = 0; qi < NQ; ++qi) {
        const int oq = (qi + qofs) & (NQ - 1);
        const float4 a4 = *(const float4*)(Ap + 4 * oq);
#pragma unroll
        for (int rr = 0; rr < 4; ++rr) {
            const int op = oq * 4 + rr;
            cf32x2* w1p = (cf32x2*)(W1c + (size_t)op * (2 * CIN) + CIN);
            f32x2 hA = {0.f, 0.f}, hB = {0.f, 0.f};
#pragma unroll
            for (int c2 = 0; c2 < CIN / 2; c2 += 2) {
                hA += w1p[c2]     * xp[c2];      // v_pk_fma_f32
                hB += w1p[c2 + 1] * xp[c2 + 1];
            }
            const float aop = rr == 0 ? a4.x : rr == 1 ? a4.y : rr == 2 ? a4.z : a4.w;
            const float h = fmaxf((hA.x + hB.x) + (hA.y + hB.y) + aop, 0.f);
            cf32x2* w2p = (cf32x2*)(W2c + (size_t)op * COUT + oh * HALF);
            const f32x2 hv = {h, h};
#pragma unroll
            for (int o = 0; o < HALF / 2; ++o)
                uacc[o] += w2p[o] * hv;          // v_pk_fma_f32
        }
    }

    // per-half 6 -> 1 max tree over neighbor waves
    if (w6 >= 3) {
#pragma unroll
        for (int o = 0; o < HALF / 2; ++o) {
            Buf[oh][w6 - 3][lane][2 * o]     = uacc[o].x;
            Buf[oh][w6 - 3][lane][2 * o + 1] = uacc[o].y;
        }
    }
    __syncthreads();
    if (w6 < 3) {
#pragma unroll
        for (int o = 0; o < HALF / 2; ++o) {
            uacc[o].x = fmaxf(uacc[o].x, Buf[oh][w6][lane][2 * o]);
            uacc[o].y = fmaxf(uacc[o].y, Buf[oh][w6][lane][2 * o + 1]);
        }
    }
    __syncthreads();
    if (w6 == 1 || w6 == 2) {
#pragma unroll
        for (int o = 0; o < HALF / 2; ++o) {
            Buf[oh][w6][lane][2 * o]     = uacc[o].x;
            Buf[oh][w6][lane][2 * o + 1] = uacc[o].y;
        }
    }
    __syncthreads();
    if (w6 == 0) {
        float* po = out + (size_t)i * COUT + oh * HALF;
        const float* b2p = b2 + oh * HALF;
        const float* rp  = RESID ? (resid + (size_t)i * COUT + oh * HALF) : nullptr;
#pragma unroll
        for (int o = 0; o < HALF / 2; ++o) {
            float v0 = fmaxf(uacc[o].x,
                             fmaxf(Buf[oh][1][lane][2 * o], Buf[oh][2][lane][2 * o])) + b2p[2 * o];
            float v1 = fmaxf(uacc[o].y,
                             fmaxf(Buf[oh][1][lane][2 * o + 1], Buf[oh][2][lane][2 * o + 1])) + b2p[2 * o + 1];
            if (RESID) { v0 += rp[2 * o]; v1 += rp[2 * o + 1]; }
            po[2 * o]     = fmaxf(v0, 0.f);
            po[2 * o + 1] = fmaxf(v1, 0.f);
        }
    }
}

extern "C" void kernel_launch(void* const* d_in, const int* in_sizes, int n_in,
                              void* d_out, int out_size, void* d_ws, size_t ws_size,
                              hipStream_t stream) {
    const float* x    = (const float*)d_in[0];
    const float* W1_0 = (const float*)d_in[2];
    const float* b1_0 = (const float*)d_in[3];
    const float* W2_0 = (const float*)d_in[4];
    const float* b2_0 = (const float*)d_in[5];
    const float* W1_1 = (const float*)d_in[6];
    const float* b1_1 = (const float*)d_in[7];
    const float* W2_1 = (const float*)d_in[8];
    const float* b2_1 = (const float*)d_in[9];
    const float* W1_2 = (const float*)d_in[10];
    const float* b1_2 = (const float*)d_in[11];
    const float* W2_2 = (const float*)d_in[12];
    const float* b2_2 = (const float*)d_in[13];
    float* outp = (float*)d_out;

    // workspace layout
    unsigned* plist = (unsigned*)d_ws;                            // NPTS*48 u32
    float* x0  = (float*)(plist + (size_t)NPTS * 48);             // 32768 x 64
    float* x1  = x0 + (size_t)NPTS * 64;                          // 32768 x 32
    float* sqb = x1 + (size_t)NPTS * 32;                          // 32768
    float* T0  = sqb + NPTS;                                      // 64 x 64
    float* T1  = T0 + 4096;                                       // 32 x 128
    float* T2  = T1 + 4096;                                       // 64 x 64
    unsigned short* Xhi = (unsigned short*)(T2 + 4096);           // 32768 x 64 u16
    unsigned short* Xlo = Xhi + (size_t)NPTS * 64;                // 32768 x 64 u16
    int* nbr = (int*)(Xlo + (size_t)NPTS * 64);                   // 32768 x 6
    float* Abuf = (float*)(nbr + (size_t)NPTS * KNB);             // 32768 x 64

    const int fgrid  = NPTS / 64;       // prep: 4 thr/point, 512 blocks
    const int rgrid  = NPTS * 2 / 256;  // rescore: 2 thr/query, 256 blocks
    const int scgrid = 1024;            // 4096 waves of 32q x 512c
    const int pgrid  = NPTS / 64;       // 512 blocks x 768 thr

    prep_w<<<16, 256, 0, stream>>>(W1_0, W1_1, W1_2, T0, T1, T2);

    // ---- layer 0: x (32) -> x0 (64), relu ----
    prep_fused<32, 64><<<fgrid, 256, 0, stream>>>(x, T0, b1_0, Xhi, Xlo, sqb, Abuf);
    knn_scan<32><<<scgrid, 256, 0, stream>>>(Xhi, Xlo, sqb, plist);
    rescore<32><<<rgrid, 256, 0, stream>>>(x, sqb, plist, nbr);
    mlp_kernel<32, 64, false, 5><<<pgrid, 768, 0, stream>>>(x, nbr, Abuf, T0, W2_0, b2_0, nullptr, x0);

    // ---- layer 1: x0 (64) -> x1 (32), relu ----
    prep_fused<64, 32><<<fgrid, 256, 0, stream>>>(x0, T1, b1_1, Xhi, Xlo, sqb, Abuf);
    knn_scan<64><<<scgrid, 256, 0, stream>>>(Xhi, Xlo, sqb, plist);
    rescore<64><<<rgrid, 256, 0, stream>>>(x0, sqb, plist, nbr);
    mlp_kernel<64, 32, false, 4><<<pgrid, 768, 0, stream>>>(x0, nbr, Abuf, T1, W2_1, b2_1, nullptr, x1);

    // ---- layer 2: x1 (32) -> out (64), +x0 residual, relu ----
    prep_fused<32, 64><<<fgrid, 256, 0, stream>>>(x1, T2, b1_2, Xhi, Xlo, sqb, Abuf);
    knn_scan<32><<<scgrid, 256, 0, stream>>>(Xhi, Xlo, sqb, plist);
    rescore<32><<<rgrid, 256, 0, stream>>>(x1, sqb, plist, nbr);
    mlp_kernel<32, 64, true, 5><<<pgrid, 768, 0, stream>>>(x1, nbr, Abuf, T2, W2_2, b2_2, x0, outp);
}